// Round 3
// baseline (174.898 us; speedup 1.0000x reference)
//
#include <hip/hip_runtime.h>
#include <hip/hip_bf16.h>
#include <stdint.h>

typedef __bf16 bf16x8 __attribute__((ext_vector_type(8)));
typedef __bf16 bf16x4 __attribute__((ext_vector_type(4)));
typedef float  f32x4  __attribute__((ext_vector_type(4)));
typedef short  s16x4  __attribute__((ext_vector_type(4)));
typedef unsigned short u16_t;

#define MFMA(a, b, c)   __builtin_amdgcn_mfma_f32_16x16x32_bf16((a), (b), (c), 0, 0, 0)
#define MFMA16(a, b, c) __builtin_amdgcn_mfma_f32_16x16x16bf16_1k((a), (b), (c), 0, 0, 0)

// async global->LDS, 16B per lane; LDS dest is wave-uniform base + lane*16
__device__ __forceinline__ void cp16(const void* g, void* l) {
  __builtin_amdgcn_global_load_lds(
      (const __attribute__((address_space(1))) unsigned int*)g,
      (__attribute__((address_space(3))) unsigned int*)l, 16, 0, 0);
}

// ---------------- kernel 1: fused x-convert + W-transpose-convert ----------------
__global__ __launch_bounds__(256) void k_prep(const float* __restrict__ x,
                                              const float* __restrict__ W0,
                                              const float* __restrict__ W1,
                                              const float* __restrict__ W2,
                                              u16_t* __restrict__ xb,
                                              u16_t* __restrict__ Wt) {
  __shared__ u16_t T[64][65];
  int bx = blockIdx.x, t = threadIdx.x;
  if (bx < 4096) {
    int i = bx * 256 + t;
    float4 f = ((const float4*)x)[i];
    bf16x4 o = {(__bf16)f.x, (__bf16)f.y, (__bf16)f.z, (__bf16)f.w};
    *(bf16x4*)&xb[(size_t)i * 4] = o;
    return;
  }
  int j = bx - 4096;
  int nx = j & 15, ny = (j >> 4) & 15, z = j >> 8;
  const float* W = z == 0 ? W0 : (z == 1 ? W1 : W2);
  int k0 = ny * 64, n0 = nx * 64;
#pragma unroll
  for (int i = 0; i < 16; i++) {
    int e = i * 256 + t, r = e >> 6, c = e & 63;
    __bf16 hv = (__bf16)W[(size_t)(k0 + r) * 1024 + n0 + c];
    T[r][c] = *(u16_t*)&hv;
  }
  __syncthreads();
  size_t base = ((size_t)z * 1024 + n0) * 1024 + k0;
#pragma unroll
  for (int i = 0; i < 16; i++) {
    int e = i * 256 + t, r = e >> 6, c = e & 63;
    Wt[base + (size_t)r * 1024 + c] = T[c][r];
  }
}

// ---------------- kernel 2: fused QKV GEMM, 256x256 tile, 8-wave, 4-phase/K-tile ----------------
// (unchanged; measured ~neutral vs 2-barrier 128^2 after clock-noise correction — kept.
// Counted-vmcnt schedule: WAITV(8)@P1 / WAITV(4)@P3, never 0 in steady state. Known
// residual flaws vs m201: 192 blocks (64 CUs idle), 4-way ds_read spread from k-half split.)
__global__ __launch_bounds__(512, 2) void k_gemm_qkv(
    const u16_t* __restrict__ A, const u16_t* __restrict__ Bt,
    const float* __restrict__ bq, const float* __restrict__ bk,
    const float* __restrict__ bv,
    u16_t* __restrict__ Qo, u16_t* __restrict__ Ko, u16_t* __restrict__ Vo) {
  __shared__ u16_t smem[65536];          // 128 KB
  u16_t* As = smem;                      // [buf:16384][half:8192][row*32 + phys_chunk*8]
  u16_t* Bs = smem + 32768;

  const int tid = threadIdx.x, lane = tid & 63, wv = tid >> 6;
  const int quad = lane >> 4, col = lane & 15;
  const int wm = wv >> 2, wn = wv & 3;   // 2x4 wave grid; wave owns 128x64 of C

  int bid = blockIdx.x;
  int wg = (bid & 7) * 24 + (bid >> 3);
  const int tn = (wg % 12) << 8, tm = (wg / 12) << 8;

  const int r16 = lane >> 2, c4 = lane & 3;
  const int srow = wv * 16 + r16;                  // 0..127 (+128 for second load)
  const int skoff = ((c4 ^ (r16 & 3)) << 3);       // pre-swizzled source chunk (u16)
  const int sdst = srow * 32 + (c4 << 3);          // == wave_base + lane*16B
  const size_t gA0 = (size_t)(tm + srow) * 1024 + skoff;
  const size_t gB0 = (size_t)(tn + srow) * 1024 + skoff;

  f32x4 acc[8][4] = {};

#define STAGE(kt, h, b) do {                                   \
    int d_ = (b) * 16384 + (h) * 8192 + sdst;                  \
    size_t s_ = (size_t)(kt) * 64 + (h) * 32;                  \
    cp16(A + gA0 + s_, As + d_);                               \
    cp16(A + gA0 + s_ + (size_t)128 * 1024, As + d_ + 4096);   \
    cp16(Bt + gB0 + s_, Bs + d_);                              \
    cp16(Bt + gB0 + s_ + (size_t)128 * 1024, Bs + d_ + 4096);  \
  } while (0)

#define BAR()    asm volatile("s_barrier" ::: "memory")
#define WAITV(N) asm volatile("s_waitcnt vmcnt(" #N ")" ::: "memory")
#define WAITL()  asm volatile("s_waitcnt lgkmcnt(0)" ::: "memory")
#define SCHED0() __builtin_amdgcn_sched_barrier(0)

  STAGE(0, 0, 0);
  STAGE(0, 1, 0);
  WAITV(4);
  BAR();

  const int swz8 = (((lane >> 4) ^ (col & 3)) << 3);
  const int abase = (wm * 128 + col) * 32 + swz8;
  const int bbase = (wn * 64 + col) * 32 + swz8;

  for (int t = 0; t < 16; ++t) {
    const int cur = t & 1, nxt = cur ^ 1;
    const u16_t* Ap = As + cur * 16384;
    const u16_t* Bp = Bs + cur * 16384;
    bf16x8 af[4], bf[4];

    // ---- P0: ks=0, mt 0-3 ----
#pragma unroll
    for (int i = 0; i < 4; i++) af[i] = *(const bf16x8*)&Ap[abase + i * 512];
#pragma unroll
    for (int i = 0; i < 4; i++) bf[i] = *(const bf16x8*)&Bp[bbase + i * 512];
    if (t + 1 < 16) STAGE(t + 1, 0, nxt);
    BAR(); WAITL(); SCHED0();
    __builtin_amdgcn_s_setprio(1);
#pragma unroll
    for (int i = 0; i < 4; i++)
#pragma unroll
      for (int j = 0; j < 4; j++) acc[i][j] = MFMA(af[i], bf[j], acc[i][j]);
    __builtin_amdgcn_s_setprio(0);
    BAR();

    // ---- P1: ks=0, mt 4-7 (reuse bf) ----
#pragma unroll
    for (int i = 0; i < 4; i++) af[i] = *(const bf16x8*)&Ap[abase + (i + 4) * 512];
    if (t + 1 < 16) { STAGE(t + 1, 1, nxt); WAITV(8); }  // publish (t,h1)
    else            { WAITV(0); }                        // final tile: drain h1
    BAR(); WAITL(); SCHED0();
    __builtin_amdgcn_s_setprio(1);
#pragma unroll
    for (int i = 0; i < 4; i++)
#pragma unroll
      for (int j = 0; j < 4; j++) acc[i + 4][j] = MFMA(af[i], bf[j], acc[i + 4][j]);
    __builtin_amdgcn_s_setprio(0);
    BAR();

    // ---- P2: ks=1, mt 0-3 ----
#pragma unroll
    for (int i = 0; i < 4; i++) af[i] = *(const bf16x8*)&Ap[8192 + abase + i * 512];
#pragma unroll
    for (int i = 0; i < 4; i++) bf[i] = *(const bf16x8*)&Bp[8192 + bbase + i * 512];
    BAR(); WAITL(); SCHED0();
    __builtin_amdgcn_s_setprio(1);
#pragma unroll
    for (int i = 0; i < 4; i++)
#pragma unroll
      for (int j = 0; j < 4; j++) acc[i][j] = MFMA(af[i], bf[j], acc[i][j]);
    __builtin_amdgcn_s_setprio(0);
    BAR();

    // ---- P3: ks=1, mt 4-7 ----
#pragma unroll
    for (int i = 0; i < 4; i++) af[i] = *(const bf16x8*)&Ap[8192 + abase + (i + 4) * 512];
    if (t + 1 < 16) WAITV(4);   // publish (t+1,h0); (t+1,h1) stays in flight
    WAITL();                    // reads of cur buf done before bar (overwrite hazard)
    BAR(); SCHED0();
    __builtin_amdgcn_s_setprio(1);
#pragma unroll
    for (int i = 0; i < 4; i++)
#pragma unroll
      for (int j = 0; j < 4; j++) acc[i + 4][j] = MFMA(af[i], bf[j], acc[i + 4][j]);
    __builtin_amdgcn_s_setprio(0);
    BAR();
  }

#undef STAGE

  const int mat = tn >> 10;
  const float* bias = mat == 0 ? bq : (mat == 1 ? bk : bv);
  if (mat == 2) {
#pragma unroll
    for (int nt = 0; nt < 4; nt++) {
      int gn = tn + wn * 64 + nt * 16 + col;
      int d = gn & 1023, h = d >> 6, dk = d & 63;
      float bb = bias[d];
#pragma unroll
      for (int mt = 0; mt < 8; mt++) {
        int gm = tm + wm * 128 + mt * 16 + quad * 4;
        int b = gm >> 11, s = gm & 2047;
        bf16x4 pk4;
#pragma unroll
        for (int r = 0; r < 4; r++) pk4[r] = (__bf16)(acc[mt][nt][r] + bb);
        *(bf16x4*)&Vo[((size_t)((b * 16 + h) * 64 + dk)) * 2048 + s] = pk4;
      }
    }
  } else {
    u16_t* O = mat == 0 ? Qo : Ko;
    const float scl = mat == 0 ? 0.18033688011112042f : 1.0f;  // log2(e)/8 in Q
#pragma unroll
    for (int nt = 0; nt < 4; nt++) {
      int gn = tn + wn * 64 + nt * 16 + col;
      int d = gn & 1023, h = d >> 6, dk = d & 63;
      float bb = bias[d];
#pragma unroll
      for (int mt = 0; mt < 8; mt++) {
#pragma unroll
        for (int r = 0; r < 4; r++) {
          int gm = tm + wm * 128 + mt * 16 + quad * 4 + r;
          int b = gm >> 11, s = gm & 2047;
          __bf16 hv = (__bf16)((acc[mt][nt][r] + bb) * scl);
          O[((size_t)((b * 16 + h) * 2048 + s)) * 64 + dk] = *(u16_t*)&hv;
        }
      }
    }
  }
}

// ---------------- kernel 3: fused attention (v9 = v8 + T15 delayed-PV + T5 setprio) ----------------
// 4 waves (qh x kh), wave = 32q x 32k per 64-key stage; P in registers.
// T15: PV delayed one K-tile -> QK^T(kt) and PV(kt-1) are independent MFMA streams;
// exp(kt) overlaps PV MFMA latency. V staged one step behind K (V(kt) staged during
// kt, read at kt+1) -- same 2-deep dbuf, no extra LDS. P ping-pongs between two
// statically-indexed register sets (pfA/pfB) via even/odd step macro (rule #20).
__global__ __launch_bounds__(256, 4) void k_attn(const u16_t* __restrict__ Q,
                                                 const u16_t* __restrict__ K,
                                                 const u16_t* __restrict__ Vt,
                                                 float* __restrict__ out) {
  __shared__ u16_t smem[20480];        // 40 KB
  u16_t* Qs  = smem;                   // 8 KB: Q staging (then reduction buffer)
  u16_t* Ksb = smem + 4096;            // 16 KB dbuf: K tiles [64k][64d]
  u16_t* Vsb = smem + 12288;           // 16 KB dbuf: V^T tiles [64d][64k]
  const int tid = threadIdx.x, lane = tid & 63, wv = tid >> 6;
  const int quad = lane >> 4, col = lane & 15;
  const int qh = wv >> 1, kh = wv & 1;

  // XCD swizzle: bid&7 = XCD, 4 heads per XCD -> K/V (2 MB) fit 4 MB L2
  const int bid = blockIdx.x;
  const int bh = (bid & 7) + 8 * ((bid >> 3) >> 5);
  const int qt = (bid >> 3) & 31;
  const int b = bh >> 4, h = bh & 15;
  const int r8 = lane >> 3, c8 = lane & 7;

  const u16_t* Qg = Q + ((size_t)bh * 2048 + qt * 64) * 64;
  const u16_t* Kg = K + (size_t)bh * 2048 * 64;
  const u16_t* Vg = Vt + (size_t)bh * 64 * 2048;

  // prologue staging: Q + K0 only (V0 staged inside step kt=0)
#pragma unroll
  for (int i = 0; i < 2; i++) {
    int c = wv * 2 + i;
    int row = c * 8 + r8;
    int lch = c8 ^ r8;
    cp16(Qg + (size_t)row * 64 + lch * 8, Qs + c * 512 + lane * 8);
    cp16(Kg + (size_t)row * 64 + lch * 8, Ksb + c * 512 + lane * 8);
  }
  __syncthreads();

  // Q fragments (this wave's 32 q) -> registers
  bf16x8 qf[2][2];
#pragma unroll
  for (int nt = 0; nt < 2; nt++)
#pragma unroll
    for (int ks = 0; ks < 2; ks++) {
      int row = qh * 32 + nt * 16 + col;
      qf[nt][ks] = *(const bf16x8*)&Qs[row * 64 + (((ks * 4 + quad) ^ (row & 7)) * 8)];
    }

  const short one_bf = (short)0x3F80;  // bf16 1.0
  s16x4 ones4 = {one_bf, one_bf, one_bf, one_bf};

  f32x4 ao[2][4] = {};
  f32x4 dn[2] = {};
  s16x4 pfA[2][2] = {}, pfB[2][2] = {};

  // one pipeline step: stage K(KT+1)->Ksb[CUR^1], V(KT)->Vsb[CUR];
  // QK^T(KT) from Ksb[CUR]; PV(KT-1) from Vsb[CUR^1] with PFR; exp -> PFW.
#define ATTN_STEP(KT, CUR, PFW, PFR, DO_PV) do {                                      \
    const u16_t* Kc = Ksb + (CUR) * 4096;                                             \
    const u16_t* Vp = Vsb + ((CUR) ^ 1) * 4096;                                       \
    u16_t* Kn = Ksb + ((CUR) ^ 1) * 4096;                                             \
    u16_t* Vn = Vsb + (CUR) * 4096;                                                   \
    _Pragma("unroll")                                                                 \
    for (int i = 0; i < 2; i++) {                                                     \
      int c = wv * 2 + i;                                                             \
      int row = c * 8 + r8;                                                           \
      int lch = c8 ^ r8;                                                              \
      if ((KT) + 1 < 32)                                                              \
        cp16(Kg + (size_t)((KT) + 1) * 4096 + (size_t)row * 64 + lch * 8,             \
             Kn + c * 512 + lane * 8);                                                \
      cp16(Vg + (size_t)row * 2048 + (KT) * 64 + lch * 8,                             \
           Vn + c * 512 + lane * 8);                                                  \
    }                                                                                 \
    f32x4 sc[2][2] = {};                                                              \
    __builtin_amdgcn_s_setprio(1);                                                    \
    _Pragma("unroll")                                                                 \
    for (int ks = 0; ks < 2; ks++) {                                                  \
      bf16x8 kf[2];                                                                   \
      _Pragma("unroll")                                                               \
      for (int mt = 0; mt < 2; mt++) {                                                \
        int row = kh * 32 + mt * 16 + col;                                            \
        kf[mt] = *(const bf16x8*)&Kc[row * 64 + (((ks * 4 + quad) ^ (row & 7)) * 8)]; \
      }                                                                               \
      _Pragma("unroll")                                                               \
      for (int mt = 0; mt < 2; mt++)                                                  \
        _Pragma("unroll")                                                             \
        for (int nt = 0; nt < 2; nt++)                                                \
          sc[mt][nt] = MFMA(kf[mt], qf[nt][ks], sc[mt][nt]);                          \
    }                                                                                 \
    if (DO_PV) {                                                                      \
      _Pragma("unroll")                                                               \
      for (int mt = 0; mt < 2; mt++) {                                                \
        _Pragma("unroll")                                                             \
        for (int dt = 0; dt < 4; dt++) {                                              \
          int row = dt * 16 + col;                                                    \
          int c = kh * 4 + mt * 2 + (quad >> 1);                                      \
          int addr = row * 64 + ((c ^ (row & 7)) * 8) + (quad & 1) * 4;               \
          s16x4 vf = *(const s16x4*)&Vp[addr];                                        \
          _Pragma("unroll")                                                           \
          for (int nt = 0; nt < 2; nt++)                                              \
            ao[nt][dt] = MFMA16(PFR[mt][nt], vf, ao[nt][dt]);                         \
        }                                                                             \
      }                                                                               \
    }                                                                                 \
    __builtin_amdgcn_s_setprio(0);                                                    \
    _Pragma("unroll")                                                                 \
    for (int mt = 0; mt < 2; mt++)                                                    \
      _Pragma("unroll")                                                               \
      for (int nt = 0; nt < 2; nt++) {                                                \
        _Pragma("unroll")                                                             \
        for (int r = 0; r < 4; r++) {                                                 \
          __bf16 e = (__bf16)__builtin_amdgcn_exp2f(sc[mt][nt][r]);                   \
          PFW[mt][nt][r] = *(short*)&e;                                               \
        }                                                                             \
        dn[nt] = MFMA16(PFW[mt][nt], ones4, dn[nt]);                                  \
      }                                                                               \
    __syncthreads();                                                                  \
  } while (0)

#pragma unroll 1
  for (int kt2 = 0; kt2 < 16; kt2++) {
    int kt0 = kt2 * 2;
    ATTN_STEP(kt0,     0, pfA, pfB, (kt0 > 0));
    ATTN_STEP(kt0 + 1, 1, pfB, pfA, 1);
  }
#undef ATTN_STEP

  // epilogue PV: pf(31) is in pfB, V(31) in Vsb buffer 1 (published by last barrier)
  {
    const u16_t* Vp = Vsb + 4096;
#pragma unroll
    for (int mt = 0; mt < 2; mt++) {
#pragma unroll
      for (int dt = 0; dt < 4; dt++) {
        int row = dt * 16 + col;
        int c = kh * 4 + mt * 2 + (quad >> 1);
        int addr = row * 64 + ((c ^ (row & 7)) * 8) + (quad & 1) * 4;
        s16x4 vf = *(const s16x4*)&Vp[addr];
#pragma unroll
        for (int nt = 0; nt < 2; nt++)
          ao[nt][dt] = MFMA16(pfB[mt][nt], vf, ao[nt][dt]);
      }
    }
  }

  // cross-wave merge over kh: kh=1 dumps partials, kh=0 adds + normalizes + stores
  // (red spans bytes 8192..29184; epilogue PV read Vbuf1 = bytes 32768.. -- disjoint)
  float* red = (float*)(smem + 4096);  // K/V region dead now
  const int rb = (qh * 64 + lane) * 41;
  if (kh == 1) {
#pragma unroll
    for (int nt = 0; nt < 2; nt++) {
#pragma unroll
      for (int dt = 0; dt < 4; dt++)
#pragma unroll
        for (int r = 0; r < 4; r++)
          red[rb + (nt * 4 + dt) * 4 + r] = ao[nt][dt][r];
#pragma unroll
      for (int r = 0; r < 4; r++)
        red[rb + 32 + nt * 4 + r] = dn[nt][r];
    }
  }
  __syncthreads();
  if (kh == 0) {
#pragma unroll
    for (int nt = 0; nt < 2; nt++) {
      float inv[4];
#pragma unroll
      for (int r = 0; r < 4; r++)
        inv[r] = 1.0f / (dn[nt][r] + red[rb + 32 + nt * 4 + r] + 1e-8f);
#pragma unroll
      for (int dt = 0; dt < 4; dt++) {
#pragma unroll
        for (int r = 0; r < 4; r++) {
          float v = (ao[nt][dt][r] + red[rb + (nt * 4 + dt) * 4 + r]) * inv[r];
          int s = qt * 64 + qh * 32 + nt * 16 + quad * 4 + r;
          out[((size_t)b * 2048 + s) * 1024 + h * 64 + dt * 16 + col] = v;
        }
      }
    }
  }
}

// ---------------- launcher ----------------
extern "C" void kernel_launch(void* const* d_in, const int* in_sizes, int n_in,
                              void* d_out, int out_size, void* d_ws, size_t ws_size,
                              hipStream_t stream) {
  const float* x  = (const float*)d_in[0];
  const float* Wq = (const float*)d_in[1];
  const float* bq = (const float*)d_in[2];
  const float* Wk = (const float*)d_in[3];
  const float* bk = (const float*)d_in[4];
  const float* Wv = (const float*)d_in[5];
  const float* bv = (const float*)d_in[6];
  float* out = (float*)d_out;

  char* ws = (char*)d_ws;
  u16_t* xb  = (u16_t*)(ws);                 // 8 MB   x bf16 [4096][1024]
  u16_t* Wt  = (u16_t*)(ws + 8388608);       // 6 MB   Wt bf16 [3072][1024]
  u16_t* Qb  = (u16_t*)(ws + 14680064);      // 8 MB   Q bf16 [bh][s][dk] (pre-scaled)
  u16_t* Kb  = (u16_t*)(ws + 23068672);      // 8 MB   K bf16 [bh][s][dk]
  u16_t* Vtb = (u16_t*)(ws + 31457280);      // 8 MB   V^T bf16 [bh][dk][s]

  hipLaunchKernelGGL(k_prep, dim3(4864), dim3(256), 0, stream, x, Wq, Wk, Wv, xb, Wt);
  hipLaunchKernelGGL(k_gemm_qkv, dim3(192), dim3(512), 0, stream,
                     xb, Wt, bq, bk, bv, Qb, Kb, Vtb);
  hipLaunchKernelGGL(k_attn, dim3(1024), dim3(256), 0, stream, Qb, Kb, Vtb, out);
}

// Round 4
// 172.023 us; speedup vs baseline: 1.0167x; 1.0167x over previous
//
#include <hip/hip_runtime.h>
#include <hip/hip_bf16.h>
#include <stdint.h>

typedef __bf16 bf16x8 __attribute__((ext_vector_type(8)));
typedef __bf16 bf16x4 __attribute__((ext_vector_type(4)));
typedef float  f32x4  __attribute__((ext_vector_type(4)));
typedef short  s16x4  __attribute__((ext_vector_type(4)));
typedef short  s16x8  __attribute__((ext_vector_type(8)));
typedef unsigned short u16_t;

#define MFMA(a, b, c)   __builtin_amdgcn_mfma_f32_16x16x32_bf16((a), (b), (c), 0, 0, 0)

// concat two s16x4 halves into a bf16x8 MFMA operand
__device__ __forceinline__ bf16x8 cat8(s16x4 a, s16x4 b) {
  s16x8 t = __builtin_shufflevector(a, b, 0, 1, 2, 3, 4, 5, 6, 7);
  return *(bf16x8*)&t;
}

// async global->LDS, 16B per lane; LDS dest is wave-uniform base + lane*16
__device__ __forceinline__ void cp16(const void* g, void* l) {
  __builtin_amdgcn_global_load_lds(
      (const __attribute__((address_space(1))) unsigned int*)g,
      (__attribute__((address_space(3))) unsigned int*)l, 16, 0, 0);
}

// ---------------- kernel 1: fused x-convert + W-transpose-convert ----------------
__global__ __launch_bounds__(256) void k_prep(const float* __restrict__ x,
                                              const float* __restrict__ W0,
                                              const float* __restrict__ W1,
                                              const float* __restrict__ W2,
                                              u16_t* __restrict__ xb,
                                              u16_t* __restrict__ Wt) {
  __shared__ u16_t T[64][65];
  int bx = blockIdx.x, t = threadIdx.x;
  if (bx < 4096) {
    int i = bx * 256 + t;
    float4 f = ((const float4*)x)[i];
    bf16x4 o = {(__bf16)f.x, (__bf16)f.y, (__bf16)f.z, (__bf16)f.w};
    *(bf16x4*)&xb[(size_t)i * 4] = o;
    return;
  }
  int j = bx - 4096;
  int nx = j & 15, ny = (j >> 4) & 15, z = j >> 8;
  const float* W = z == 0 ? W0 : (z == 1 ? W1 : W2);
  int k0 = ny * 64, n0 = nx * 64;
#pragma unroll
  for (int i = 0; i < 16; i++) {
    int e = i * 256 + t, r = e >> 6, c = e & 63;
    __bf16 hv = (__bf16)W[(size_t)(k0 + r) * 1024 + n0 + c];
    T[r][c] = *(u16_t*)&hv;
  }
  __syncthreads();
  size_t base = ((size_t)z * 1024 + n0) * 1024 + k0;
#pragma unroll
  for (int i = 0; i < 16; i++) {
    int e = i * 256 + t, r = e >> 6, c = e & 63;
    Wt[base + (size_t)r * 1024 + c] = T[c][r];
  }
}

// ---------------- kernel 2: fused QKV GEMM, 256x256 tile, 8-wave, 4-phase/K-tile ----------------
// (unchanged; measured ~neutral vs 2-barrier 128^2 after clock-noise correction — kept.
// Counted-vmcnt schedule: WAITV(8)@P1 / WAITV(4)@P3, never 0 in steady state. Known
// residual flaws vs m201: 192 blocks (64 CUs idle), 4-way ds_read spread from k-half split.)
__global__ __launch_bounds__(512, 2) void k_gemm_qkv(
    const u16_t* __restrict__ A, const u16_t* __restrict__ Bt,
    const float* __restrict__ bq, const float* __restrict__ bk,
    const float* __restrict__ bv,
    u16_t* __restrict__ Qo, u16_t* __restrict__ Ko, u16_t* __restrict__ Vo) {
  __shared__ u16_t smem[65536];          // 128 KB
  u16_t* As = smem;                      // [buf:16384][half:8192][row*32 + phys_chunk*8]
  u16_t* Bs = smem + 32768;

  const int tid = threadIdx.x, lane = tid & 63, wv = tid >> 6;
  const int quad = lane >> 4, col = lane & 15;
  const int wm = wv >> 2, wn = wv & 3;   // 2x4 wave grid; wave owns 128x64 of C

  int bid = blockIdx.x;
  int wg = (bid & 7) * 24 + (bid >> 3);
  const int tn = (wg % 12) << 8, tm = (wg / 12) << 8;

  const int r16 = lane >> 2, c4 = lane & 3;
  const int srow = wv * 16 + r16;                  // 0..127 (+128 for second load)
  const int skoff = ((c4 ^ (r16 & 3)) << 3);       // pre-swizzled source chunk (u16)
  const int sdst = srow * 32 + (c4 << 3);          // == wave_base + lane*16B
  const size_t gA0 = (size_t)(tm + srow) * 1024 + skoff;
  const size_t gB0 = (size_t)(tn + srow) * 1024 + skoff;

  f32x4 acc[8][4] = {};

#define STAGE(kt, h, b) do {                                   \
    int d_ = (b) * 16384 + (h) * 8192 + sdst;                  \
    size_t s_ = (size_t)(kt) * 64 + (h) * 32;                  \
    cp16(A + gA0 + s_, As + d_);                               \
    cp16(A + gA0 + s_ + (size_t)128 * 1024, As + d_ + 4096);   \
    cp16(Bt + gB0 + s_, Bs + d_);                              \
    cp16(Bt + gB0 + s_ + (size_t)128 * 1024, Bs + d_ + 4096);  \
  } while (0)

#define BAR()    asm volatile("s_barrier" ::: "memory")
#define WAITV(N) asm volatile("s_waitcnt vmcnt(" #N ")" ::: "memory")
#define WAITL()  asm volatile("s_waitcnt lgkmcnt(0)" ::: "memory")
#define SCHED0() __builtin_amdgcn_sched_barrier(0)

  STAGE(0, 0, 0);
  STAGE(0, 1, 0);
  WAITV(4);
  BAR();

  const int swz8 = (((lane >> 4) ^ (col & 3)) << 3);
  const int abase = (wm * 128 + col) * 32 + swz8;
  const int bbase = (wn * 64 + col) * 32 + swz8;

  for (int t = 0; t < 16; ++t) {
    const int cur = t & 1, nxt = cur ^ 1;
    const u16_t* Ap = As + cur * 16384;
    const u16_t* Bp = Bs + cur * 16384;
    bf16x8 af[4], bf[4];

    // ---- P0: ks=0, mt 0-3 ----
#pragma unroll
    for (int i = 0; i < 4; i++) af[i] = *(const bf16x8*)&Ap[abase + i * 512];
#pragma unroll
    for (int i = 0; i < 4; i++) bf[i] = *(const bf16x8*)&Bp[bbase + i * 512];
    if (t + 1 < 16) STAGE(t + 1, 0, nxt);
    BAR(); WAITL(); SCHED0();
    __builtin_amdgcn_s_setprio(1);
#pragma unroll
    for (int i = 0; i < 4; i++)
#pragma unroll
      for (int j = 0; j < 4; j++) acc[i][j] = MFMA(af[i], bf[j], acc[i][j]);
    __builtin_amdgcn_s_setprio(0);
    BAR();

    // ---- P1: ks=0, mt 4-7 (reuse bf) ----
#pragma unroll
    for (int i = 0; i < 4; i++) af[i] = *(const bf16x8*)&Ap[abase + (i + 4) * 512];
    if (t + 1 < 16) { STAGE(t + 1, 1, nxt); WAITV(8); }  // publish (t,h1)
    else            { WAITV(0); }                        // final tile: drain h1
    BAR(); WAITL(); SCHED0();
    __builtin_amdgcn_s_setprio(1);
#pragma unroll
    for (int i = 0; i < 4; i++)
#pragma unroll
      for (int j = 0; j < 4; j++) acc[i + 4][j] = MFMA(af[i], bf[j], acc[i + 4][j]);
    __builtin_amdgcn_s_setprio(0);
    BAR();

    // ---- P2: ks=1, mt 0-3 ----
#pragma unroll
    for (int i = 0; i < 4; i++) af[i] = *(const bf16x8*)&Ap[8192 + abase + i * 512];
#pragma unroll
    for (int i = 0; i < 4; i++) bf[i] = *(const bf16x8*)&Bp[8192 + bbase + i * 512];
    BAR(); WAITL(); SCHED0();
    __builtin_amdgcn_s_setprio(1);
#pragma unroll
    for (int i = 0; i < 4; i++)
#pragma unroll
      for (int j = 0; j < 4; j++) acc[i][j] = MFMA(af[i], bf[j], acc[i][j]);
    __builtin_amdgcn_s_setprio(0);
    BAR();

    // ---- P3: ks=1, mt 4-7 ----
#pragma unroll
    for (int i = 0; i < 4; i++) af[i] = *(const bf16x8*)&Ap[8192 + abase + (i + 4) * 512];
    if (t + 1 < 16) WAITV(4);   // publish (t+1,h0); (t+1,h1) stays in flight
    WAITL();                    // reads of cur buf done before bar (overwrite hazard)
    BAR(); SCHED0();
    __builtin_amdgcn_s_setprio(1);
#pragma unroll
    for (int i = 0; i < 4; i++)
#pragma unroll
      for (int j = 0; j < 4; j++) acc[i + 4][j] = MFMA(af[i], bf[j], acc[i + 4][j]);
    __builtin_amdgcn_s_setprio(0);
    BAR();
  }

#undef STAGE

  const int mat = tn >> 10;
  const float* bias = mat == 0 ? bq : (mat == 1 ? bk : bv);
  if (mat == 2) {
#pragma unroll
    for (int nt = 0; nt < 4; nt++) {
      int gn = tn + wn * 64 + nt * 16 + col;
      int d = gn & 1023, h = d >> 6, dk = d & 63;
      float bb = bias[d];
#pragma unroll
      for (int mt = 0; mt < 8; mt++) {
        int gm = tm + wm * 128 + mt * 16 + quad * 4;
        int b = gm >> 11, s = gm & 2047;
        bf16x4 pk4;
#pragma unroll
        for (int r = 0; r < 4; r++) pk4[r] = (__bf16)(acc[mt][nt][r] + bb);
        *(bf16x4*)&Vo[((size_t)((b * 16 + h) * 64 + dk)) * 2048 + s] = pk4;
      }
    }
  } else {
    u16_t* O = mat == 0 ? Qo : Ko;
    const float scl = mat == 0 ? 0.18033688011112042f : 1.0f;  // log2(e)/8 in Q
#pragma unroll
    for (int nt = 0; nt < 4; nt++) {
      int gn = tn + wn * 64 + nt * 16 + col;
      int d = gn & 1023, h = d >> 6, dk = d & 63;
      float bb = bias[d];
#pragma unroll
      for (int mt = 0; mt < 8; mt++) {
#pragma unroll
        for (int r = 0; r < 4; r++) {
          int gm = tm + wm * 128 + mt * 16 + quad * 4 + r;
          int b = gm >> 11, s = gm & 2047;
          __bf16 hv = (__bf16)((acc[mt][nt][r] + bb) * scl);
          O[((size_t)((b * 16 + h) * 2048 + s)) * 64 + dk] = *(u16_t*)&hv;
        }
      }
    }
  }
}

// ---------------- kernel 3: fused attention (v10 = v9 + PV at K=32) ----------------
// 4 waves (qh x kh), wave = 32q x 32k per 64-key stage; P in registers; T15 delayed-PV.
// PV upgrade: k-slot order inside an MFMA is a free permutation as long as A and B
// agree. Slot (quad,j) := phys key (j>>2)*16 + quad*4 + (j&3). Then the 16x16x32
// A-frag is exactly concat(pf[0][nt], pf[1][nt]) (zero cross-lane movement) and the
// B-frag is concat of the two V^T 8B groups already loaded for mt=0/1. PV: 16 MFMA16
// -> 8 MFMA32; dn: 4 MFMA16 -> 2 MFMA32. Halves PV MFMA-pipe time (~29 -> ~21 us).
__global__ __launch_bounds__(256, 4) void k_attn(const u16_t* __restrict__ Q,
                                                 const u16_t* __restrict__ K,
                                                 const u16_t* __restrict__ Vt,
                                                 float* __restrict__ out) {
  __shared__ u16_t smem[20480];        // 40 KB
  u16_t* Qs  = smem;                   // 8 KB: Q staging (then reduction buffer)
  u16_t* Ksb = smem + 4096;            // 16 KB dbuf: K tiles [64k][64d]
  u16_t* Vsb = smem + 12288;           // 16 KB dbuf: V^T tiles [64d][64k]
  const int tid = threadIdx.x, lane = tid & 63, wv = tid >> 6;
  const int quad = lane >> 4, col = lane & 15;
  const int qh = wv >> 1, kh = wv & 1;

  // XCD swizzle: bid&7 = XCD, 4 heads per XCD -> K/V (2 MB) fit 4 MB L2
  const int bid = blockIdx.x;
  const int bh = (bid & 7) + 8 * ((bid >> 3) >> 5);
  const int qt = (bid >> 3) & 31;
  const int b = bh >> 4, h = bh & 15;
  const int r8 = lane >> 3, c8 = lane & 7;

  const u16_t* Qg = Q + ((size_t)bh * 2048 + qt * 64) * 64;
  const u16_t* Kg = K + (size_t)bh * 2048 * 64;
  const u16_t* Vg = Vt + (size_t)bh * 64 * 2048;

  // prologue staging: Q + K0 only (V0 staged inside step kt=0)
#pragma unroll
  for (int i = 0; i < 2; i++) {
    int c = wv * 2 + i;
    int row = c * 8 + r8;
    int lch = c8 ^ r8;
    cp16(Qg + (size_t)row * 64 + lch * 8, Qs + c * 512 + lane * 8);
    cp16(Kg + (size_t)row * 64 + lch * 8, Ksb + c * 512 + lane * 8);
  }
  __syncthreads();

  // Q fragments (this wave's 32 q) -> registers
  bf16x8 qf[2][2];
#pragma unroll
  for (int nt = 0; nt < 2; nt++)
#pragma unroll
    for (int ks = 0; ks < 2; ks++) {
      int row = qh * 32 + nt * 16 + col;
      qf[nt][ks] = *(const bf16x8*)&Qs[row * 64 + (((ks * 4 + quad) ^ (row & 7)) * 8)];
    }

  const short one_bf = (short)0x3F80;  // bf16 1.0
  s16x8 ones8s = {one_bf, one_bf, one_bf, one_bf, one_bf, one_bf, one_bf, one_bf};
  const bf16x8 ones8 = *(bf16x8*)&ones8s;

  f32x4 ao[2][4] = {};
  f32x4 dn[2] = {};
  s16x4 pfA[2][2] = {}, pfB[2][2] = {};

  // one pipeline step: stage K(KT+1)->Ksb[CUR^1], V(KT)->Vsb[CUR];
  // QK^T(KT) from Ksb[CUR]; PV(KT-1) from Vsb[CUR^1] with PFR (K=32); exp -> PFW.
#define ATTN_STEP(KT, CUR, PFW, PFR, DO_PV) do {                                      \
    const u16_t* Kc = Ksb + (CUR) * 4096;                                             \
    const u16_t* Vp = Vsb + ((CUR) ^ 1) * 4096;                                       \
    u16_t* Kn = Ksb + ((CUR) ^ 1) * 4096;                                             \
    u16_t* Vn = Vsb + (CUR) * 4096;                                                   \
    _Pragma("unroll")                                                                 \
    for (int i = 0; i < 2; i++) {                                                     \
      int c = wv * 2 + i;                                                             \
      int row = c * 8 + r8;                                                           \
      int lch = c8 ^ r8;                                                              \
      if ((KT) + 1 < 32)                                                              \
        cp16(Kg + (size_t)((KT) + 1) * 4096 + (size_t)row * 64 + lch * 8,             \
             Kn + c * 512 + lane * 8);                                                \
      cp16(Vg + (size_t)row * 2048 + (KT) * 64 + lch * 8,                             \
           Vn + c * 512 + lane * 8);                                                  \
    }                                                                                 \
    f32x4 sc[2][2] = {};                                                              \
    __builtin_amdgcn_s_setprio(1);                                                    \
    _Pragma("unroll")                                                                 \
    for (int ks = 0; ks < 2; ks++) {                                                  \
      bf16x8 kf[2];                                                                   \
      _Pragma("unroll")                                                               \
      for (int mt = 0; mt < 2; mt++) {                                                \
        int row = kh * 32 + mt * 16 + col;                                            \
        kf[mt] = *(const bf16x8*)&Kc[row * 64 + (((ks * 4 + quad) ^ (row & 7)) * 8)]; \
      }                                                                               \
      _Pragma("unroll")                                                               \
      for (int mt = 0; mt < 2; mt++)                                                  \
        _Pragma("unroll")                                                             \
        for (int nt = 0; nt < 2; nt++)                                                \
          sc[mt][nt] = MFMA(kf[mt], qf[nt][ks], sc[mt][nt]);                          \
    }                                                                                 \
    if (DO_PV) {                                                                      \
      bf16x8 pa0 = cat8(PFR[0][0], PFR[1][0]);                                        \
      bf16x8 pa1 = cat8(PFR[0][1], PFR[1][1]);                                        \
      _Pragma("unroll")                                                               \
      for (int dt = 0; dt < 4; dt++) {                                                \
        int row = dt * 16 + col;                                                      \
        int c0 = kh * 4 + (quad >> 1);                                                \
        int a0 = row * 64 + ((c0 ^ (row & 7)) * 8) + (quad & 1) * 4;                  \
        int a1 = row * 64 + (((c0 + 2) ^ (row & 7)) * 8) + (quad & 1) * 4;            \
        bf16x8 vv = cat8(*(const s16x4*)&Vp[a0], *(const s16x4*)&Vp[a1]);             \
        ao[0][dt] = MFMA(pa0, vv, ao[0][dt]);                                         \
        ao[1][dt] = MFMA(pa1, vv, ao[1][dt]);                                         \
      }                                                                               \
    }                                                                                 \
    __builtin_amdgcn_s_setprio(0);                                                    \
    _Pragma("unroll")                                                                 \
    for (int mt = 0; mt < 2; mt++)                                                    \
      _Pragma("unroll")                                                               \
      for (int nt = 0; nt < 2; nt++)                                                  \
        _Pragma("unroll")                                                             \
        for (int r = 0; r < 4; r++) {                                                 \
          __bf16 e = (__bf16)__builtin_amdgcn_exp2f(sc[mt][nt][r]);                   \
          PFW[mt][nt][r] = *(short*)&e;                                               \
        }                                                                             \
    _Pragma("unroll")                                                                 \
    for (int nt = 0; nt < 2; nt++)                                                    \
      dn[nt] = MFMA(cat8(PFW[0][nt], PFW[1][nt]), ones8, dn[nt]);                     \
    __syncthreads();                                                                  \
  } while (0)

#pragma unroll 1
  for (int kt2 = 0; kt2 < 16; kt2++) {
    int kt0 = kt2 * 2;
    ATTN_STEP(kt0,     0, pfA, pfB, (kt0 > 0));
    ATTN_STEP(kt0 + 1, 1, pfB, pfA, 1);
  }
#undef ATTN_STEP

  // epilogue PV: pf(31) is in pfB, V(31) in Vsb buffer 1 (published by last barrier)
  {
    const u16_t* Vp = Vsb + 4096;
    bf16x8 pa0 = cat8(pfB[0][0], pfB[1][0]);
    bf16x8 pa1 = cat8(pfB[0][1], pfB[1][1]);
#pragma unroll
    for (int dt = 0; dt < 4; dt++) {
      int row = dt * 16 + col;
      int c0 = kh * 4 + (quad >> 1);
      int a0 = row * 64 + ((c0 ^ (row & 7)) * 8) + (quad & 1) * 4;
      int a1 = row * 64 + (((c0 + 2) ^ (row & 7)) * 8) + (quad & 1) * 4;
      bf16x8 vv = cat8(*(const s16x4*)&Vp[a0], *(const s16x4*)&Vp[a1]);
      ao[0][dt] = MFMA(pa0, vv, ao[0][dt]);
      ao[1][dt] = MFMA(pa1, vv, ao[1][dt]);
    }
  }

  // cross-wave merge over kh: kh=1 dumps partials, kh=0 adds + normalizes + stores
  // (red spans bytes 8192..29184; epilogue PV read Vbuf1 = bytes 32768.. -- disjoint)
  float* red = (float*)(smem + 4096);  // K/V region dead now
  const int rb = (qh * 64 + lane) * 41;
  if (kh == 1) {
#pragma unroll
    for (int nt = 0; nt < 2; nt++) {
#pragma unroll
      for (int dt = 0; dt < 4; dt++)
#pragma unroll
        for (int r = 0; r < 4; r++)
          red[rb + (nt * 4 + dt) * 4 + r] = ao[nt][dt][r];
#pragma unroll
      for (int r = 0; r < 4; r++)
        red[rb + 32 + nt * 4 + r] = dn[nt][r];
    }
  }
  __syncthreads();
  if (kh == 0) {
#pragma unroll
    for (int nt = 0; nt < 2; nt++) {
      float inv[4];
#pragma unroll
      for (int r = 0; r < 4; r++)
        inv[r] = 1.0f / (dn[nt][r] + red[rb + 32 + nt * 4 + r] + 1e-8f);
#pragma unroll
      for (int dt = 0; dt < 4; dt++) {
#pragma unroll
        for (int r = 0; r < 4; r++) {
          float v = (ao[nt][dt][r] + red[rb + (nt * 4 + dt) * 4 + r]) * inv[r];
          int s = qt * 64 + qh * 32 + nt * 16 + quad * 4 + r;
          out[((size_t)b * 2048 + s) * 1024 + h * 64 + dt * 16 + col] = v;
        }
      }
    }
  }
}

// ---------------- launcher ----------------
extern "C" void kernel_launch(void* const* d_in, const int* in_sizes, int n_in,
                              void* d_out, int out_size, void* d_ws, size_t ws_size,
                              hipStream_t stream) {
  const float* x  = (const float*)d_in[0];
  const float* Wq = (const float*)d_in[1];
  const float* bq = (const float*)d_in[2];
  const float* Wk = (const float*)d_in[3];
  const float* bk = (const float*)d_in[4];
  const float* Wv = (const float*)d_in[5];
  const float* bv = (const float*)d_in[6];
  float* out = (float*)d_out;

  char* ws = (char*)d_ws;
  u16_t* xb  = (u16_t*)(ws);                 // 8 MB   x bf16 [4096][1024]
  u16_t* Wt  = (u16_t*)(ws + 8388608);       // 6 MB   Wt bf16 [3072][1024]
  u16_t* Qb  = (u16_t*)(ws + 14680064);      // 8 MB   Q bf16 [bh][s][dk] (pre-scaled)
  u16_t* Kb  = (u16_t*)(ws + 23068672);      // 8 MB   K bf16 [bh][s][dk]
  u16_t* Vtb = (u16_t*)(ws + 31457280);      // 8 MB   V^T bf16 [bh][dk][s]

  hipLaunchKernelGGL(k_prep, dim3(4864), dim3(256), 0, stream, x, Wq, Wk, Wv, xb, Wt);
  hipLaunchKernelGGL(k_gemm_qkv, dim3(192), dim3(512), 0, stream,
                     xb, Wt, bq, bk, bv, Qb, Kb, Vtb);
  hipLaunchKernelGGL(k_attn, dim3(1024), dim3(256), 0, stream, Qb, Kb, Vtb, out);
}

// Round 5
// 170.309 us; speedup vs baseline: 1.0269x; 1.0101x over previous
//
#include <hip/hip_runtime.h>
#include <hip/hip_bf16.h>
#include <stdint.h>

typedef __bf16 bf16x8 __attribute__((ext_vector_type(8)));
typedef __bf16 bf16x4 __attribute__((ext_vector_type(4)));
typedef float  f32x4  __attribute__((ext_vector_type(4)));
typedef short  s16x4  __attribute__((ext_vector_type(4)));
typedef short  s16x8  __attribute__((ext_vector_type(8)));
typedef unsigned short u16_t;

#define MFMA(a, b, c)   __builtin_amdgcn_mfma_f32_16x16x32_bf16((a), (b), (c), 0, 0, 0)

// concat two s16x4 halves into a bf16x8 MFMA operand
__device__ __forceinline__ bf16x8 cat8(s16x4 a, s16x4 b) {
  s16x8 t = __builtin_shufflevector(a, b, 0, 1, 2, 3, 4, 5, 6, 7);
  return *(bf16x8*)&t;
}

// async global->LDS, 16B per lane; LDS dest is wave-uniform base + lane*16
__device__ __forceinline__ void cp16(const void* g, void* l) {
  __builtin_amdgcn_global_load_lds(
      (const __attribute__((address_space(1))) unsigned int*)g,
      (__attribute__((address_space(3))) unsigned int*)l, 16, 0, 0);
}

// ---------------- kernel 1: fused x-convert + W-transpose-convert ----------------
__global__ __launch_bounds__(256) void k_prep(const float* __restrict__ x,
                                              const float* __restrict__ W0,
                                              const float* __restrict__ W1,
                                              const float* __restrict__ W2,
                                              u16_t* __restrict__ xb,
                                              u16_t* __restrict__ Wt) {
  __shared__ u16_t T[64][65];
  int bx = blockIdx.x, t = threadIdx.x;
  if (bx < 4096) {
    int i = bx * 256 + t;
    float4 f = ((const float4*)x)[i];
    bf16x4 o = {(__bf16)f.x, (__bf16)f.y, (__bf16)f.z, (__bf16)f.w};
    *(bf16x4*)&xb[(size_t)i * 4] = o;
    return;
  }
  int j = bx - 4096;
  int nx = j & 15, ny = (j >> 4) & 15, z = j >> 8;
  const float* W = z == 0 ? W0 : (z == 1 ? W1 : W2);
  int k0 = ny * 64, n0 = nx * 64;
#pragma unroll
  for (int i = 0; i < 16; i++) {
    int e = i * 256 + t, r = e >> 6, c = e & 63;
    __bf16 hv = (__bf16)W[(size_t)(k0 + r) * 1024 + n0 + c];
    T[r][c] = *(u16_t*)&hv;
  }
  __syncthreads();
  size_t base = ((size_t)z * 1024 + n0) * 1024 + k0;
#pragma unroll
  for (int i = 0; i < 16; i++) {
    int e = i * 256 + t, r = e >> 6, c = e & 63;
    Wt[base + (size_t)r * 1024 + c] = T[c][r];
  }
}

// ---------------- kernel 2: fused QKV GEMM, 256x256 tile, 8-wave, 4-phase/K-tile ----------------
// Round-5 fix: LDS bank conflict. The k-half split gives 32-elem (64B) rows; the old
// XOR (chunk ^ (col&3)) left col/col+4 aliased (row distance 256B == 0 mod 128B) ->
// 4-way ds_read conflict (2.36M cycles measured, LDS-read > MFMA pipe time). New XOR
// uses (row>>1)&3: col/col+2 differ in bit0, col/col+4 in bit1; only col/col+8 alias
// -> uniform 2-way = free (m136). Applied identically on staging source (rule #21:
// pre-swizzled global source, linear cp16 dest) and ds_read side.
__global__ __launch_bounds__(512, 2) void k_gemm_qkv(
    const u16_t* __restrict__ A, const u16_t* __restrict__ Bt,
    const float* __restrict__ bq, const float* __restrict__ bk,
    const float* __restrict__ bv,
    u16_t* __restrict__ Qo, u16_t* __restrict__ Ko, u16_t* __restrict__ Vo) {
  __shared__ u16_t smem[65536];          // 128 KB
  u16_t* As = smem;                      // [buf:16384][half:8192][row*32 + phys_chunk*8]
  u16_t* Bs = smem + 32768;

  const int tid = threadIdx.x, lane = tid & 63, wv = tid >> 6;
  const int quad = lane >> 4, col = lane & 15;
  const int wm = wv >> 2, wn = wv & 3;   // 2x4 wave grid; wave owns 128x64 of C

  int bid = blockIdx.x;
  int wg = (bid & 7) * 24 + (bid >> 3);
  const int tn = (wg % 12) << 8, tm = (wg / 12) << 8;

  const int r16 = lane >> 2, c4 = lane & 3;
  const int srow = wv * 16 + r16;                  // 0..127 (+128 for second load)
  const int skoff = ((c4 ^ ((r16 >> 1) & 3)) << 3);  // pre-swizzled source chunk (u16)
  const int sdst = srow * 32 + (c4 << 3);          // == wave_base + lane*16B
  const size_t gA0 = (size_t)(tm + srow) * 1024 + skoff;
  const size_t gB0 = (size_t)(tn + srow) * 1024 + skoff;

  f32x4 acc[8][4] = {};

#define STAGE(kt, h, b) do {                                   \
    int d_ = (b) * 16384 + (h) * 8192 + sdst;                  \
    size_t s_ = (size_t)(kt) * 64 + (h) * 32;                  \
    cp16(A + gA0 + s_, As + d_);                               \
    cp16(A + gA0 + s_ + (size_t)128 * 1024, As + d_ + 4096);   \
    cp16(Bt + gB0 + s_, Bs + d_);                              \
    cp16(Bt + gB0 + s_ + (size_t)128 * 1024, Bs + d_ + 4096);  \
  } while (0)

#define BAR()    asm volatile("s_barrier" ::: "memory")
#define WAITV(N) asm volatile("s_waitcnt vmcnt(" #N ")" ::: "memory")
#define WAITL()  asm volatile("s_waitcnt lgkmcnt(0)" ::: "memory")
#define SCHED0() __builtin_amdgcn_sched_barrier(0)

  STAGE(0, 0, 0);
  STAGE(0, 1, 0);
  WAITV(4);
  BAR();

  // read-side swizzle: read rows are 16m+col so (row>>1)&3 == (col>>1)&3
  const int swz8 = (((lane >> 4) ^ ((col >> 1) & 3)) << 3);
  const int abase = (wm * 128 + col) * 32 + swz8;
  const int bbase = (wn * 64 + col) * 32 + swz8;

  for (int t = 0; t < 16; ++t) {
    const int cur = t & 1, nxt = cur ^ 1;
    const u16_t* Ap = As + cur * 16384;
    const u16_t* Bp = Bs + cur * 16384;
    bf16x8 af[4], bf[4];

    // ---- P0: ks=0, mt 0-3 ----
#pragma unroll
    for (int i = 0; i < 4; i++) af[i] = *(const bf16x8*)&Ap[abase + i * 512];
#pragma unroll
    for (int i = 0; i < 4; i++) bf[i] = *(const bf16x8*)&Bp[bbase + i * 512];
    if (t + 1 < 16) STAGE(t + 1, 0, nxt);
    BAR(); WAITL(); SCHED0();
    __builtin_amdgcn_s_setprio(1);
#pragma unroll
    for (int i = 0; i < 4; i++)
#pragma unroll
      for (int j = 0; j < 4; j++) acc[i][j] = MFMA(af[i], bf[j], acc[i][j]);
    __builtin_amdgcn_s_setprio(0);
    BAR();

    // ---- P1: ks=0, mt 4-7 (reuse bf) ----
#pragma unroll
    for (int i = 0; i < 4; i++) af[i] = *(const bf16x8*)&Ap[abase + (i + 4) * 512];
    if (t + 1 < 16) { STAGE(t + 1, 1, nxt); WAITV(8); }  // publish (t,h1)
    else            { WAITV(0); }                        // final tile: drain h1
    BAR(); WAITL(); SCHED0();
    __builtin_amdgcn_s_setprio(1);
#pragma unroll
    for (int i = 0; i < 4; i++)
#pragma unroll
      for (int j = 0; j < 4; j++) acc[i + 4][j] = MFMA(af[i], bf[j], acc[i + 4][j]);
    __builtin_amdgcn_s_setprio(0);
    BAR();

    // ---- P2: ks=1, mt 0-3 ----
#pragma unroll
    for (int i = 0; i < 4; i++) af[i] = *(const bf16x8*)&Ap[8192 + abase + i * 512];
#pragma unroll
    for (int i = 0; i < 4; i++) bf[i] = *(const bf16x8*)&Bp[8192 + bbase + i * 512];
    BAR(); WAITL(); SCHED0();
    __builtin_amdgcn_s_setprio(1);
#pragma unroll
    for (int i = 0; i < 4; i++)
#pragma unroll
      for (int j = 0; j < 4; j++) acc[i][j] = MFMA(af[i], bf[j], acc[i][j]);
    __builtin_amdgcn_s_setprio(0);
    BAR();

    // ---- P3: ks=1, mt 4-7 ----
#pragma unroll
    for (int i = 0; i < 4; i++) af[i] = *(const bf16x8*)&Ap[8192 + abase + (i + 4) * 512];
    if (t + 1 < 16) WAITV(4);   // publish (t+1,h0); (t+1,h1) stays in flight
    WAITL();                    // reads of cur buf done before bar (overwrite hazard)
    BAR(); SCHED0();
    __builtin_amdgcn_s_setprio(1);
#pragma unroll
    for (int i = 0; i < 4; i++)
#pragma unroll
      for (int j = 0; j < 4; j++) acc[i + 4][j] = MFMA(af[i], bf[j], acc[i + 4][j]);
    __builtin_amdgcn_s_setprio(0);
    BAR();
  }

#undef STAGE

  const int mat = tn >> 10;
  const float* bias = mat == 0 ? bq : (mat == 1 ? bk : bv);
  if (mat == 2) {
#pragma unroll
    for (int nt = 0; nt < 4; nt++) {
      int gn = tn + wn * 64 + nt * 16 + col;
      int d = gn & 1023, h = d >> 6, dk = d & 63;
      float bb = bias[d];
#pragma unroll
      for (int mt = 0; mt < 8; mt++) {
        int gm = tm + wm * 128 + mt * 16 + quad * 4;
        int b = gm >> 11, s = gm & 2047;
        bf16x4 pk4;
#pragma unroll
        for (int r = 0; r < 4; r++) pk4[r] = (__bf16)(acc[mt][nt][r] + bb);
        *(bf16x4*)&Vo[((size_t)((b * 16 + h) * 64 + dk)) * 2048 + s] = pk4;
      }
    }
  } else {
    u16_t* O = mat == 0 ? Qo : Ko;
    const float scl = mat == 0 ? 0.18033688011112042f : 1.0f;  // log2(e)/8 in Q
#pragma unroll
    for (int nt = 0; nt < 4; nt++) {
      int gn = tn + wn * 64 + nt * 16 + col;
      int d = gn & 1023, h = d >> 6, dk = d & 63;
      float bb = bias[d];
#pragma unroll
      for (int mt = 0; mt < 8; mt++) {
#pragma unroll
        for (int r = 0; r < 4; r++) {
          int gm = tm + wm * 128 + mt * 16 + quad * 4 + r;
          int b = gm >> 11, s = gm & 2047;
          __bf16 hv = (__bf16)((acc[mt][nt][r] + bb) * scl);
          O[((size_t)((b * 16 + h) * 2048 + s)) * 64 + dk] = *(u16_t*)&hv;
        }
      }
    }
  }
}

// ---------------- kernel 3: fused attention (v10 = v9 + PV at K=32) ----------------
// 4 waves (qh x kh), wave = 32q x 32k per 64-key stage; P in registers; T15 delayed-PV.
// PV upgrade: k-slot order inside an MFMA is a free permutation as long as A and B
// agree. Slot (quad,j) := phys key (j>>2)*16 + quad*4 + (j&3). Then the 16x16x32
// A-frag is exactly concat(pf[0][nt], pf[1][nt]) (zero cross-lane movement) and the
// B-frag is concat of the two V^T 8B groups already loaded for mt=0/1. PV: 16 MFMA16
// -> 8 MFMA32; dn: 4 MFMA16 -> 2 MFMA32.
__global__ __launch_bounds__(256, 4) void k_attn(const u16_t* __restrict__ Q,
                                                 const u16_t* __restrict__ K,
                                                 const u16_t* __restrict__ Vt,
                                                 float* __restrict__ out) {
  __shared__ u16_t smem[20480];        // 40 KB
  u16_t* Qs  = smem;                   // 8 KB: Q staging (then reduction buffer)
  u16_t* Ksb = smem + 4096;            // 16 KB dbuf: K tiles [64k][64d]
  u16_t* Vsb = smem + 12288;           // 16 KB dbuf: V^T tiles [64d][64k]
  const int tid = threadIdx.x, lane = tid & 63, wv = tid >> 6;
  const int quad = lane >> 4, col = lane & 15;
  const int qh = wv >> 1, kh = wv & 1;

  // XCD swizzle: bid&7 = XCD, 4 heads per XCD -> K/V (2 MB) fit 4 MB L2
  const int bid = blockIdx.x;
  const int bh = (bid & 7) + 8 * ((bid >> 3) >> 5);
  const int qt = (bid >> 3) & 31;
  const int b = bh >> 4, h = bh & 15;
  const int r8 = lane >> 3, c8 = lane & 7;

  const u16_t* Qg = Q + ((size_t)bh * 2048 + qt * 64) * 64;
  const u16_t* Kg = K + (size_t)bh * 2048 * 64;
  const u16_t* Vg = Vt + (size_t)bh * 64 * 2048;

  // prologue staging: Q + K0 only (V0 staged inside step kt=0)
#pragma unroll
  for (int i = 0; i < 2; i++) {
    int c = wv * 2 + i;
    int row = c * 8 + r8;
    int lch = c8 ^ r8;
    cp16(Qg + (size_t)row * 64 + lch * 8, Qs + c * 512 + lane * 8);
    cp16(Kg + (size_t)row * 64 + lch * 8, Ksb + c * 512 + lane * 8);
  }
  __syncthreads();

  // Q fragments (this wave's 32 q) -> registers
  bf16x8 qf[2][2];
#pragma unroll
  for (int nt = 0; nt < 2; nt++)
#pragma unroll
    for (int ks = 0; ks < 2; ks++) {
      int row = qh * 32 + nt * 16 + col;
      qf[nt][ks] = *(const bf16x8*)&Qs[row * 64 + (((ks * 4 + quad) ^ (row & 7)) * 8)];
    }

  const short one_bf = (short)0x3F80;  // bf16 1.0
  s16x8 ones8s = {one_bf, one_bf, one_bf, one_bf, one_bf, one_bf, one_bf, one_bf};
  const bf16x8 ones8 = *(bf16x8*)&ones8s;

  f32x4 ao[2][4] = {};
  f32x4 dn[2] = {};
  s16x4 pfA[2][2] = {}, pfB[2][2] = {};

  // one pipeline step: stage K(KT+1)->Ksb[CUR^1], V(KT)->Vsb[CUR];
  // QK^T(KT) from Ksb[CUR]; PV(KT-1) from Vsb[CUR^1] with PFR (K=32); exp -> PFW.
#define ATTN_STEP(KT, CUR, PFW, PFR, DO_PV) do {                                      \
    const u16_t* Kc = Ksb + (CUR) * 4096;                                             \
    const u16_t* Vp = Vsb + ((CUR) ^ 1) * 4096;                                       \
    u16_t* Kn = Ksb + ((CUR) ^ 1) * 4096;                                             \
    u16_t* Vn = Vsb + (CUR) * 4096;                                                   \
    _Pragma("unroll")                                                                 \
    for (int i = 0; i < 2; i++) {                                                     \
      int c = wv * 2 + i;                                                             \
      int row = c * 8 + r8;                                                           \
      int lch = c8 ^ r8;                                                              \
      if ((KT) + 1 < 32)                                                              \
        cp16(Kg + (size_t)((KT) + 1) * 4096 + (size_t)row * 64 + lch * 8,             \
             Kn + c * 512 + lane * 8);                                                \
      cp16(Vg + (size_t)row * 2048 + (KT) * 64 + lch * 8,                             \
           Vn + c * 512 + lane * 8);                                                  \
    }                                                                                 \
    f32x4 sc[2][2] = {};                                                              \
    __builtin_amdgcn_s_setprio(1);                                                    \
    _Pragma("unroll")                                                                 \
    for (int ks = 0; ks < 2; ks++) {                                                  \
      bf16x8 kf[2];                                                                   \
      _Pragma("unroll")                                                               \
      for (int mt = 0; mt < 2; mt++) {                                                \
        int row = kh * 32 + mt * 16 + col;                                            \
        kf[mt] = *(const bf16x8*)&Kc[row * 64 + (((ks * 4 + quad) ^ (row & 7)) * 8)]; \
      }                                                                               \
      _Pragma("unroll")                                                               \
      for (int mt = 0; mt < 2; mt++)                                                  \
        _Pragma("unroll")                                                             \
        for (int nt = 0; nt < 2; nt++)                                                \
          sc[mt][nt] = MFMA(kf[mt], qf[nt][ks], sc[mt][nt]);                          \
    }                                                                                 \
    if (DO_PV) {                                                                      \
      bf16x8 pa0 = cat8(PFR[0][0], PFR[1][0]);                                        \
      bf16x8 pa1 = cat8(PFR[0][1], PFR[1][1]);                                        \
      _Pragma("unroll")                                                               \
      for (int dt = 0; dt < 4; dt++) {                                                \
        int row = dt * 16 + col;                                                      \
        int c0 = kh * 4 + (quad >> 1);                                                \
        int a0 = row * 64 + ((c0 ^ (row & 7)) * 8) + (quad & 1) * 4;                  \
        int a1 = row * 64 + (((c0 + 2) ^ (row & 7)) * 8) + (quad & 1) * 4;            \
        bf16x8 vv = cat8(*(const s16x4*)&Vp[a0], *(const s16x4*)&Vp[a1]);             \
        ao[0][dt] = MFMA(pa0, vv, ao[0][dt]);                                         \
        ao[1][dt] = MFMA(pa1, vv, ao[1][dt]);                                         \
      }                                                                               \
    }                                                                                 \
    __builtin_amdgcn_s_setprio(0);                                                    \
    _Pragma("unroll")                                                                 \
    for (int mt = 0; mt < 2; mt++)                                                    \
      _Pragma("unroll")                                                               \
      for (int nt = 0; nt < 2; nt++)                                                  \
        _Pragma("unroll")                                                             \
        for (int r = 0; r < 4; r++) {                                                 \
          __bf16 e = (__bf16)__builtin_amdgcn_exp2f(sc[mt][nt][r]);                   \
          PFW[mt][nt][r] = *(short*)&e;                                               \
        }                                                                             \
    _Pragma("unroll")                                                                 \
    for (int nt = 0; nt < 2; nt++)                                                    \
      dn[nt] = MFMA(cat8(PFW[0][nt], PFW[1][nt]), ones8, dn[nt]);                     \
    __syncthreads();                                                                  \
  } while (0)

#pragma unroll 1
  for (int kt2 = 0; kt2 < 16; kt2++) {
    int kt0 = kt2 * 2;
    ATTN_STEP(kt0,     0, pfA, pfB, (kt0 > 0));
    ATTN_STEP(kt0 + 1, 1, pfB, pfA, 1);
  }
#undef ATTN_STEP

  // epilogue PV: pf(31) is in pfB, V(31) in Vsb buffer 1 (published by last barrier)
  {
    const u16_t* Vp = Vsb + 4096;
    bf16x8 pa0 = cat8(pfB[0][0], pfB[1][0]);
    bf16x8 pa1 = cat8(pfB[0][1], pfB[1][1]);
#pragma unroll
    for (int dt = 0; dt < 4; dt++) {
      int row = dt * 16 + col;
      int c0 = kh * 4 + (quad >> 1);
      int a0 = row * 64 + ((c0 ^ (row & 7)) * 8) + (quad & 1) * 4;
      int a1 = row * 64 + (((c0 + 2) ^ (row & 7)) * 8) + (quad & 1) * 4;
      bf16x8 vv = cat8(*(const s16x4*)&Vp[a0], *(const s16x4*)&Vp[a1]);
      ao[0][dt] = MFMA(pa0, vv, ao[0][dt]);
      ao[1][dt] = MFMA(pa1, vv, ao[1][dt]);
    }
  }

  // cross-wave merge over kh: kh=1 dumps partials, kh=0 adds + normalizes + stores
  // (red spans bytes 8192..29184; epilogue PV read Vbuf1 = bytes 32768.. -- disjoint)
  float* red = (float*)(smem + 4096);  // K/V region dead now
  const int rb = (qh * 64 + lane) * 41;
  if (kh == 1) {
#pragma unroll
    for (int nt = 0; nt < 2; nt++) {
#pragma unroll
      for (int dt = 0; dt < 4; dt++)
#pragma unroll
        for (int r = 0; r < 4; r++)
          red[rb + (nt * 4 + dt) * 4 + r] = ao[nt][dt][r];
#pragma unroll
      for (int r = 0; r < 4; r++)
        red[rb + 32 + nt * 4 + r] = dn[nt][r];
    }
  }
  __syncthreads();
  if (kh == 0) {
#pragma unroll
    for (int nt = 0; nt < 2; nt++) {
      float inv[4];
#pragma unroll
      for (int r = 0; r < 4; r++)
        inv[r] = 1.0f / (dn[nt][r] + red[rb + 32 + nt * 4 + r] + 1e-8f);
#pragma unroll
      for (int dt = 0; dt < 4; dt++) {
#pragma unroll
        for (int r = 0; r < 4; r++) {
          float v = (ao[nt][dt][r] + red[rb + (nt * 4 + dt) * 4 + r]) * inv[r];
          int s = qt * 64 + qh * 32 + nt * 16 + quad * 4 + r;
          out[((size_t)b * 2048 + s) * 1024 + h * 64 + dt * 16 + col] = v;
        }
      }
    }
  }
}

// ---------------- launcher ----------------
extern "C" void kernel_launch(void* const* d_in, const int* in_sizes, int n_in,
                              void* d_out, int out_size, void* d_ws, size_t ws_size,
                              hipStream_t stream) {
  const float* x  = (const float*)d_in[0];
  const float* Wq = (const float*)d_in[1];
  const float* bq = (const float*)d_in[2];
  const float* Wk = (const float*)d_in[3];
  const float* bk = (const float*)d_in[4];
  const float* Wv = (const float*)d_in[5];
  const float* bv = (const float*)d_in[6];
  float* out = (float*)d_out;

  char* ws = (char*)d_ws;
  u16_t* xb  = (u16_t*)(ws);                 // 8 MB   x bf16 [4096][1024]
  u16_t* Wt  = (u16_t*)(ws + 8388608);       // 6 MB   Wt bf16 [3072][1024]
  u16_t* Qb  = (u16_t*)(ws + 14680064);      // 8 MB   Q bf16 [bh][s][dk] (pre-scaled)
  u16_t* Kb  = (u16_t*)(ws + 23068672);      // 8 MB   K bf16 [bh][s][dk]
  u16_t* Vtb = (u16_t*)(ws + 31457280);      // 8 MB   V^T bf16 [bh][dk][s]

  hipLaunchKernelGGL(k_prep, dim3(4864), dim3(256), 0, stream, x, Wq, Wk, Wv, xb, Wt);
  hipLaunchKernelGGL(k_gemm_qkv, dim3(192), dim3(512), 0, stream,
                     xb, Wt, bq, bk, bv, Qb, Kb, Vtb);
  hipLaunchKernelGGL(k_attn, dim3(1024), dim3(256), 0, stream, Qb, Kb, Vtb, out);
}

// Round 6
// 168.873 us; speedup vs baseline: 1.0357x; 1.0085x over previous
//
#include <hip/hip_runtime.h>
#include <hip/hip_bf16.h>
#include <stdint.h>

typedef __bf16 bf16x8 __attribute__((ext_vector_type(8)));
typedef __bf16 bf16x4 __attribute__((ext_vector_type(4)));
typedef float  f32x4  __attribute__((ext_vector_type(4)));
typedef short  s16x4  __attribute__((ext_vector_type(4)));
typedef short  s16x8  __attribute__((ext_vector_type(8)));
typedef unsigned short u16_t;

#define MFMA(a, b, c)   __builtin_amdgcn_mfma_f32_16x16x32_bf16((a), (b), (c), 0, 0, 0)

// concat two s16x4 halves into a bf16x8 MFMA operand
__device__ __forceinline__ bf16x8 cat8(s16x4 a, s16x4 b) {
  s16x8 t = __builtin_shufflevector(a, b, 0, 1, 2, 3, 4, 5, 6, 7);
  return *(bf16x8*)&t;
}
__device__ __forceinline__ bf16x8 b8(s16x8 v) {
  bf16x8 r; __builtin_memcpy(&r, &v, 16); return r;
}

// async global->LDS, 16B per lane; LDS dest is wave-uniform base + lane*16
__device__ __forceinline__ void cp16(const void* g, void* l) {
  __builtin_amdgcn_global_load_lds(
      (const __attribute__((address_space(1))) unsigned int*)g,
      (__attribute__((address_space(3))) unsigned int*)l, 16, 0, 0);
}

// ---------------- kernel 1: fused x-convert + W-transpose-convert ----------------
__global__ __launch_bounds__(256) void k_prep(const float* __restrict__ x,
                                              const float* __restrict__ W0,
                                              const float* __restrict__ W1,
                                              const float* __restrict__ W2,
                                              u16_t* __restrict__ xb,
                                              u16_t* __restrict__ Wt) {
  __shared__ u16_t T[64][65];
  int bx = blockIdx.x, t = threadIdx.x;
  if (bx < 4096) {
    int i = bx * 256 + t;
    float4 f = ((const float4*)x)[i];
    bf16x4 o = {(__bf16)f.x, (__bf16)f.y, (__bf16)f.z, (__bf16)f.w};
    *(bf16x4*)&xb[(size_t)i * 4] = o;
    return;
  }
  int j = bx - 4096;
  int nx = j & 15, ny = (j >> 4) & 15, z = j >> 8;
  const float* W = z == 0 ? W0 : (z == 1 ? W1 : W2);
  int k0 = ny * 64, n0 = nx * 64;
#pragma unroll
  for (int i = 0; i < 16; i++) {
    int e = i * 256 + t, r = e >> 6, c = e & 63;
    __bf16 hv = (__bf16)W[(size_t)(k0 + r) * 1024 + n0 + c];
    T[r][c] = *(u16_t*)&hv;
  }
  __syncthreads();
  size_t base = ((size_t)z * 1024 + n0) * 1024 + k0;
#pragma unroll
  for (int i = 0; i < 16; i++) {
    int e = i * 256 + t, r = e >> 6, c = e & 63;
    Wt[base + (size_t)r * 1024 + c] = T[c][r];
  }
}

// ---------------- kernel 2: fused QKV GEMM, 256x256 tile, 8-wave, 4-phase/K-tile ----------------
// (unchanged this round; round-5 conflict fix confirmed: dropped from 56 -> <48 us,
// out of top-5. Counted-vmcnt schedule, (row>>1)&3 chunk-XOR = uniform 2-way = free.)
__global__ __launch_bounds__(512, 2) void k_gemm_qkv(
    const u16_t* __restrict__ A, const u16_t* __restrict__ Bt,
    const float* __restrict__ bq, const float* __restrict__ bk,
    const float* __restrict__ bv,
    u16_t* __restrict__ Qo, u16_t* __restrict__ Ko, u16_t* __restrict__ Vo) {
  __shared__ u16_t smem[65536];          // 128 KB
  u16_t* As = smem;                      // [buf:16384][half:8192][row*32 + phys_chunk*8]
  u16_t* Bs = smem + 32768;

  const int tid = threadIdx.x, lane = tid & 63, wv = tid >> 6;
  const int quad = lane >> 4, col = lane & 15;
  const int wm = wv >> 2, wn = wv & 3;   // 2x4 wave grid; wave owns 128x64 of C

  int bid = blockIdx.x;
  int wg = (bid & 7) * 24 + (bid >> 3);
  const int tn = (wg % 12) << 8, tm = (wg / 12) << 8;

  const int r16 = lane >> 2, c4 = lane & 3;
  const int srow = wv * 16 + r16;                  // 0..127 (+128 for second load)
  const int skoff = ((c4 ^ ((r16 >> 1) & 3)) << 3);  // pre-swizzled source chunk (u16)
  const int sdst = srow * 32 + (c4 << 3);          // == wave_base + lane*16B
  const size_t gA0 = (size_t)(tm + srow) * 1024 + skoff;
  const size_t gB0 = (size_t)(tn + srow) * 1024 + skoff;

  f32x4 acc[8][4] = {};

#define STAGE(kt, h, b) do {                                   \
    int d_ = (b) * 16384 + (h) * 8192 + sdst;                  \
    size_t s_ = (size_t)(kt) * 64 + (h) * 32;                  \
    cp16(A + gA0 + s_, As + d_);                               \
    cp16(A + gA0 + s_ + (size_t)128 * 1024, As + d_ + 4096);   \
    cp16(Bt + gB0 + s_, Bs + d_);                              \
    cp16(Bt + gB0 + s_ + (size_t)128 * 1024, Bs + d_ + 4096);  \
  } while (0)

#define BAR()    asm volatile("s_barrier" ::: "memory")
#define WAITV(N) asm volatile("s_waitcnt vmcnt(" #N ")" ::: "memory")
#define WAITL()  asm volatile("s_waitcnt lgkmcnt(0)" ::: "memory")
#define SCHED0() __builtin_amdgcn_sched_barrier(0)

  STAGE(0, 0, 0);
  STAGE(0, 1, 0);
  WAITV(4);
  BAR();

  // read-side swizzle: read rows are 16m+col so (row>>1)&3 == (col>>1)&3
  const int swz8 = (((lane >> 4) ^ ((col >> 1) & 3)) << 3);
  const int abase = (wm * 128 + col) * 32 + swz8;
  const int bbase = (wn * 64 + col) * 32 + swz8;

  for (int t = 0; t < 16; ++t) {
    const int cur = t & 1, nxt = cur ^ 1;
    const u16_t* Ap = As + cur * 16384;
    const u16_t* Bp = Bs + cur * 16384;
    bf16x8 af[4], bf[4];

    // ---- P0: ks=0, mt 0-3 ----
#pragma unroll
    for (int i = 0; i < 4; i++) af[i] = *(const bf16x8*)&Ap[abase + i * 512];
#pragma unroll
    for (int i = 0; i < 4; i++) bf[i] = *(const bf16x8*)&Bp[bbase + i * 512];
    if (t + 1 < 16) STAGE(t + 1, 0, nxt);
    BAR(); WAITL(); SCHED0();
    __builtin_amdgcn_s_setprio(1);
#pragma unroll
    for (int i = 0; i < 4; i++)
#pragma unroll
      for (int j = 0; j < 4; j++) acc[i][j] = MFMA(af[i], bf[j], acc[i][j]);
    __builtin_amdgcn_s_setprio(0);
    BAR();

    // ---- P1: ks=0, mt 4-7 (reuse bf) ----
#pragma unroll
    for (int i = 0; i < 4; i++) af[i] = *(const bf16x8*)&Ap[abase + (i + 4) * 512];
    if (t + 1 < 16) { STAGE(t + 1, 1, nxt); WAITV(8); }  // publish (t,h1)
    else            { WAITV(0); }                        // final tile: drain h1
    BAR(); WAITL(); SCHED0();
    __builtin_amdgcn_s_setprio(1);
#pragma unroll
    for (int i = 0; i < 4; i++)
#pragma unroll
      for (int j = 0; j < 4; j++) acc[i + 4][j] = MFMA(af[i], bf[j], acc[i + 4][j]);
    __builtin_amdgcn_s_setprio(0);
    BAR();

    // ---- P2: ks=1, mt 0-3 ----
#pragma unroll
    for (int i = 0; i < 4; i++) af[i] = *(const bf16x8*)&Ap[8192 + abase + i * 512];
#pragma unroll
    for (int i = 0; i < 4; i++) bf[i] = *(const bf16x8*)&Bp[8192 + bbase + i * 512];
    BAR(); WAITL(); SCHED0();
    __builtin_amdgcn_s_setprio(1);
#pragma unroll
    for (int i = 0; i < 4; i++)
#pragma unroll
      for (int j = 0; j < 4; j++) acc[i][j] = MFMA(af[i], bf[j], acc[i][j]);
    __builtin_amdgcn_s_setprio(0);
    BAR();

    // ---- P3: ks=1, mt 4-7 ----
#pragma unroll
    for (int i = 0; i < 4; i++) af[i] = *(const bf16x8*)&Ap[8192 + abase + (i + 4) * 512];
    if (t + 1 < 16) WAITV(4);   // publish (t+1,h0); (t+1,h1) stays in flight
    WAITL();                    // reads of cur buf done before bar (overwrite hazard)
    BAR(); SCHED0();
    __builtin_amdgcn_s_setprio(1);
#pragma unroll
    for (int i = 0; i < 4; i++)
#pragma unroll
      for (int j = 0; j < 4; j++) acc[i + 4][j] = MFMA(af[i], bf[j], acc[i + 4][j]);
    __builtin_amdgcn_s_setprio(0);
    BAR();
  }

#undef STAGE

  const int mat = tn >> 10;
  const float* bias = mat == 0 ? bq : (mat == 1 ? bk : bv);
  if (mat == 2) {
#pragma unroll
    for (int nt = 0; nt < 4; nt++) {
      int gn = tn + wn * 64 + nt * 16 + col;
      int d = gn & 1023, h = d >> 6, dk = d & 63;
      float bb = bias[d];
#pragma unroll
      for (int mt = 0; mt < 8; mt++) {
        int gm = tm + wm * 128 + mt * 16 + quad * 4;
        int b = gm >> 11, s = gm & 2047;
        bf16x4 pk4;
#pragma unroll
        for (int r = 0; r < 4; r++) pk4[r] = (__bf16)(acc[mt][nt][r] + bb);
        *(bf16x4*)&Vo[((size_t)((b * 16 + h) * 64 + dk)) * 2048 + s] = pk4;
      }
    }
  } else {
    u16_t* O = mat == 0 ? Qo : Ko;
    const float scl = mat == 0 ? 0.18033688011112042f : 1.0f;  // log2(e)/8 in Q
#pragma unroll
    for (int nt = 0; nt < 4; nt++) {
      int gn = tn + wn * 64 + nt * 16 + col;
      int d = gn & 1023, h = d >> 6, dk = d & 63;
      float bb = bias[d];
#pragma unroll
      for (int mt = 0; mt < 8; mt++) {
#pragma unroll
        for (int r = 0; r < 4; r++) {
          int gm = tm + wm * 128 + mt * 16 + quad * 4 + r;
          int b = gm >> 11, s = gm & 2047;
          __bf16 hv = (__bf16)((acc[mt][nt][r] + bb) * scl);
          O[((size_t)((b * 16 + h) * 2048 + s)) * 64 + dk] = *(u16_t*)&hv;
        }
      }
    }
  }
}

// ---------------- kernel 3: fused attention (v11 = v10 + VALU trim) ----------------
// VALU-bound per round-5 counters (VALUBusy 46, MfmaUtil 31). This round: (1) P stored
// as s16x8 per nt (elem mt*4+r) -> PV/dn operands are the registers themselves, all
// P-path cat8 movs gone; (2) hoisted z4 as MFMA C-in for ks=0 (kills 16 zero-movs per
// step); (3) all loop-invariant addresses (ka/va/staging offsets) hoisted; (4) first/
// last steps peeled -> branch-free main loop. Same data placement as v10 (bit-identical).
__global__ __launch_bounds__(256, 4) void k_attn(const u16_t* __restrict__ Q,
                                                 const u16_t* __restrict__ K,
                                                 const u16_t* __restrict__ Vt,
                                                 float* __restrict__ out) {
  __shared__ u16_t smem[20480];        // 40 KB
  u16_t* Qs  = smem;                   // 8 KB: Q staging (then reduction buffer)
  u16_t* Ksb = smem + 4096;            // 16 KB dbuf: K tiles [64k][64d]
  u16_t* Vsb = smem + 12288;           // 16 KB dbuf: V^T tiles [64d][64k]
  const int tid = threadIdx.x, lane = tid & 63, wv = tid >> 6;
  const int quad = lane >> 4, col = lane & 15;
  const int qh = wv >> 1, kh = wv & 1;

  // XCD swizzle: bid&7 = XCD, 4 heads per XCD -> K/V (2 MB) fit 4 MB L2
  const int bid = blockIdx.x;
  const int bh = (bid & 7) + 8 * ((bid >> 3) >> 5);
  const int qt = (bid >> 3) & 31;
  const int b = bh >> 4, h = bh & 15;
  const int r8 = lane >> 3, c8 = lane & 7;

  const u16_t* Qg = Q + ((size_t)bh * 2048 + qt * 64) * 64;
  const u16_t* Kg = K + (size_t)bh * 2048 * 64;
  const u16_t* Vg = Vt + (size_t)bh * 64 * 2048;

  // staging geometry (hoisted): two cp16 per array per step
  const int lch  = c8 ^ r8;
  const int row0 = (wv * 2) * 8 + r8, row1 = (wv * 2 + 1) * 8 + r8;
  const int ldst0 = (wv * 2) * 512 + lane * 8;
  const int ldst1 = (wv * 2 + 1) * 512 + lane * 8;
  const int gk0 = row0 * 64 + lch * 8,   gk1 = row1 * 64 + lch * 8;
  const int gv0 = row0 * 2048 + lch * 8, gv1 = row1 * 2048 + lch * 8;

  // prologue staging: Q + K0 only (V0 staged inside step kt=0)
  cp16(Qg + gk0, Qs + ldst0);
  cp16(Qg + gk1, Qs + ldst1);
  cp16(Kg + gk0, Ksb + ldst0);
  cp16(Kg + gk1, Ksb + ldst1);
  __syncthreads();

  // Q fragments (this wave's 32 q) -> registers
  bf16x8 qf[2][2];
#pragma unroll
  for (int nt = 0; nt < 2; nt++)
#pragma unroll
    for (int ks = 0; ks < 2; ks++) {
      int row = qh * 32 + nt * 16 + col;
      qf[nt][ks] = *(const bf16x8*)&Qs[row * 64 + (((ks * 4 + quad) ^ (row & 7)) * 8)];
    }

  // hoisted fragment addresses (all loop-invariant)
  int ka[2][2];
#pragma unroll
  for (int ks = 0; ks < 2; ks++)
#pragma unroll
    for (int mt = 0; mt < 2; mt++) {
      int row = kh * 32 + mt * 16 + col;
      ka[ks][mt] = row * 64 + (((ks * 4 + quad) ^ (row & 7)) * 8);
    }
  int va0[4], va1[4];
#pragma unroll
  for (int dt = 0; dt < 4; dt++) {
    int row = dt * 16 + col;
    int cc = kh * 4 + (quad >> 1);
    va0[dt] = row * 64 + ((cc ^ (row & 7)) * 8) + (quad & 1) * 4;
    va1[dt] = row * 64 + (((cc + 2) ^ (row & 7)) * 8) + (quad & 1) * 4;
  }

  const short one_bf = (short)0x3F80;  // bf16 1.0
  s16x8 ones8s = {one_bf, one_bf, one_bf, one_bf, one_bf, one_bf, one_bf, one_bf};
  const bf16x8 ones8 = *(bf16x8*)&ones8s;
  const f32x4 z4 = {0.f, 0.f, 0.f, 0.f};

  f32x4 ao[2][4] = {};
  f32x4 dn[2] = {};
  s16x8 pA[2] = {}, pB[2] = {};   // P as s16x8 per nt, elem = mt*4+r

  // one pipeline step: stage K(KT+1)->Ksb[CUR^1], V(KT)->Vsb[CUR];
  // QK^T(KT) from Ksb[CUR]; PV(KT-1) from Vsb[CUR^1] with PFR (K=32); exp -> PFW.
#define ATTN_STEP(KT, CUR, PFW, PFR, DO_PV, DO_PRE) do {                              \
    const u16_t* Kc = Ksb + (CUR) * 4096;                                             \
    const u16_t* Vp = Vsb + ((CUR) ^ 1) * 4096;                                       \
    u16_t* Kn = Ksb + ((CUR) ^ 1) * 4096;                                             \
    u16_t* Vn = Vsb + (CUR) * 4096;                                                   \
    if (DO_PRE) {                                                                     \
      const u16_t* kb = Kg + (size_t)((KT) + 1) * 4096;                               \
      cp16(kb + gk0, Kn + ldst0);                                                     \
      cp16(kb + gk1, Kn + ldst1);                                                     \
    }                                                                                 \
    {                                                                                 \
      const u16_t* vb = Vg + (size_t)(KT) * 64;                                       \
      cp16(vb + gv0, Vn + ldst0);                                                     \
      cp16(vb + gv1, Vn + ldst1);                                                     \
    }                                                                                 \
    f32x4 sc[2][2];                                                                   \
    __builtin_amdgcn_s_setprio(1);                                                    \
    {                                                                                 \
      bf16x8 kf0 = *(const bf16x8*)&Kc[ka[0][0]];                                     \
      bf16x8 kf1 = *(const bf16x8*)&Kc[ka[0][1]];                                     \
      sc[0][0] = MFMA(kf0, qf[0][0], z4);                                             \
      sc[0][1] = MFMA(kf0, qf[1][0], z4);                                             \
      sc[1][0] = MFMA(kf1, qf[0][0], z4);                                             \
      sc[1][1] = MFMA(kf1, qf[1][0], z4);                                             \
      kf0 = *(const bf16x8*)&Kc[ka[1][0]];                                            \
      kf1 = *(const bf16x8*)&Kc[ka[1][1]];                                            \
      sc[0][0] = MFMA(kf0, qf[0][1], sc[0][0]);                                       \
      sc[0][1] = MFMA(kf0, qf[1][1], sc[0][1]);                                       \
      sc[1][0] = MFMA(kf1, qf[0][1], sc[1][0]);                                       \
      sc[1][1] = MFMA(kf1, qf[1][1], sc[1][1]);                                       \
    }                                                                                 \
    if (DO_PV) {                                                                      \
      bf16x8 pa0 = b8(PFR[0]);                                                        \
      bf16x8 pa1 = b8(PFR[1]);                                                        \
      _Pragma("unroll")                                                               \
      for (int dt = 0; dt < 4; dt++) {                                                \
        bf16x8 vv = cat8(*(const s16x4*)&Vp[va0[dt]], *(const s16x4*)&Vp[va1[dt]]);   \
        ao[0][dt] = MFMA(pa0, vv, ao[0][dt]);                                         \
        ao[1][dt] = MFMA(pa1, vv, ao[1][dt]);                                         \
      }                                                                               \
    }                                                                                 \
    __builtin_amdgcn_s_setprio(0);                                                    \
    _Pragma("unroll")                                                                 \
    for (int mt = 0; mt < 2; mt++)                                                    \
      _Pragma("unroll")                                                               \
      for (int nt = 0; nt < 2; nt++)                                                  \
        _Pragma("unroll")                                                             \
        for (int r = 0; r < 4; r++) {                                                 \
          __bf16 e = (__bf16)__builtin_amdgcn_exp2f(sc[mt][nt][r]);                   \
          PFW[nt][mt * 4 + r] = *(short*)&e;                                          \
        }                                                                             \
    dn[0] = MFMA(b8(PFW[0]), ones8, dn[0]);                                           \
    dn[1] = MFMA(b8(PFW[1]), ones8, dn[1]);                                           \
    __syncthreads();                                                                  \
  } while (0)

  // peeled: kt=0 (no PV), kt=1; main loop kt=2..29; peeled kt=30, kt=31 (no K prefetch)
  ATTN_STEP(0, 0, pA, pB, 0, 1);
  ATTN_STEP(1, 1, pB, pA, 1, 1);
#pragma unroll 1
  for (int kt2 = 1; kt2 < 15; kt2++) {
    int kt0 = kt2 * 2;
    ATTN_STEP(kt0,     0, pA, pB, 1, 1);
    ATTN_STEP(kt0 + 1, 1, pB, pA, 1, 1);
  }
  ATTN_STEP(30, 0, pA, pB, 1, 1);
  ATTN_STEP(31, 1, pB, pA, 1, 0);
#undef ATTN_STEP

  // epilogue PV: P(31) is in pB, V(31) in Vsb buffer 1 (published by last barrier)
  {
    const u16_t* Vp = Vsb + 4096;
    bf16x8 pa0 = b8(pB[0]);
    bf16x8 pa1 = b8(pB[1]);
#pragma unroll
    for (int dt = 0; dt < 4; dt++) {
      bf16x8 vv = cat8(*(const s16x4*)&Vp[va0[dt]], *(const s16x4*)&Vp[va1[dt]]);
      ao[0][dt] = MFMA(pa0, vv, ao[0][dt]);
      ao[1][dt] = MFMA(pa1, vv, ao[1][dt]);
    }
  }

  // cross-wave merge over kh: kh=1 dumps partials, kh=0 adds + normalizes + stores
  float* red = (float*)(smem + 4096);  // K/V region dead now
  const int rb = (qh * 64 + lane) * 41;
  if (kh == 1) {
#pragma unroll
    for (int nt = 0; nt < 2; nt++) {
#pragma unroll
      for (int dt = 0; dt < 4; dt++)
#pragma unroll
        for (int r = 0; r < 4; r++)
          red[rb + (nt * 4 + dt) * 4 + r] = ao[nt][dt][r];
#pragma unroll
      for (int r = 0; r < 4; r++)
        red[rb + 32 + nt * 4 + r] = dn[nt][r];
    }
  }
  __syncthreads();
  if (kh == 0) {
#pragma unroll
    for (int nt = 0; nt < 2; nt++) {
      float inv[4];
#pragma unroll
      for (int r = 0; r < 4; r++)
        inv[r] = 1.0f / (dn[nt][r] + red[rb + 32 + nt * 4 + r] + 1e-8f);
#pragma unroll
      for (int dt = 0; dt < 4; dt++) {
#pragma unroll
        for (int r = 0; r < 4; r++) {
          float v = (ao[nt][dt][r] + red[rb + (nt * 4 + dt) * 4 + r]) * inv[r];
          int s = qt * 64 + qh * 32 + nt * 16 + quad * 4 + r;
          out[((size_t)b * 2048 + s) * 1024 + h * 64 + dt * 16 + col] = v;
        }
      }
    }
  }
}

// ---------------- launcher ----------------
extern "C" void kernel_launch(void* const* d_in, const int* in_sizes, int n_in,
                              void* d_out, int out_size, void* d_ws, size_t ws_size,
                              hipStream_t stream) {
  const float* x  = (const float*)d_in[0];
  const float* Wq = (const float*)d_in[1];
  const float* bq = (const float*)d_in[2];
  const float* Wk = (const float*)d_in[3];
  const float* bk = (const float*)d_in[4];
  const float* Wv = (const float*)d_in[5];
  const float* bv = (const float*)d_in[6];
  float* out = (float*)d_out;

  char* ws = (char*)d_ws;
  u16_t* xb  = (u16_t*)(ws);                 // 8 MB   x bf16 [4096][1024]
  u16_t* Wt  = (u16_t*)(ws + 8388608);       // 6 MB   Wt bf16 [3072][1024]
  u16_t* Qb  = (u16_t*)(ws + 14680064);      // 8 MB   Q bf16 [bh][s][dk] (pre-scaled)
  u16_t* Kb  = (u16_t*)(ws + 23068672);      // 8 MB   K bf16 [bh][s][dk]
  u16_t* Vtb = (u16_t*)(ws + 31457280);      // 8 MB   V^T bf16 [bh][dk][s]

  hipLaunchKernelGGL(k_prep, dim3(4864), dim3(256), 0, stream, x, Wq, Wk, Wv, xb, Wt);
  hipLaunchKernelGGL(k_gemm_qkv, dim3(192), dim3(512), 0, stream,
                     xb, Wt, bq, bk, bv, Qb, Kb, Vtb);
  hipLaunchKernelGGL(k_attn, dim3(1024), dim3(256), 0, stream, Qb, Kb, Vtb, out);
}

// Round 7
// 167.800 us; speedup vs baseline: 1.0423x; 1.0064x over previous
//
#include <hip/hip_runtime.h>
#include <hip/hip_bf16.h>
#include <stdint.h>

typedef __bf16 bf16x8 __attribute__((ext_vector_type(8)));
typedef __bf16 bf16x4 __attribute__((ext_vector_type(4)));
typedef float  f32x4  __attribute__((ext_vector_type(4)));
typedef short  s16x4  __attribute__((ext_vector_type(4)));
typedef short  s16x8  __attribute__((ext_vector_type(8)));
typedef unsigned short u16_t;

#define MFMA(a, b, c)   __builtin_amdgcn_mfma_f32_16x16x32_bf16((a), (b), (c), 0, 0, 0)

// concat two s16x4 halves into a bf16x8 MFMA operand
__device__ __forceinline__ bf16x8 cat8(s16x4 a, s16x4 b) {
  s16x8 t = __builtin_shufflevector(a, b, 0, 1, 2, 3, 4, 5, 6, 7);
  return *(bf16x8*)&t;
}
__device__ __forceinline__ bf16x8 b8(s16x8 v) {
  bf16x8 r; __builtin_memcpy(&r, &v, 16); return r;
}

// async global->LDS, 16B per lane; LDS dest is wave-uniform base + lane*16
__device__ __forceinline__ void cp16(const void* g, void* l) {
  __builtin_amdgcn_global_load_lds(
      (const __attribute__((address_space(1))) unsigned int*)g,
      (__attribute__((address_space(3))) unsigned int*)l, 16, 0, 0);
}

// ---------------- kernel 1: fused x-convert + W-transpose-convert ----------------
__global__ __launch_bounds__(256) void k_prep(const float* __restrict__ x,
                                              const float* __restrict__ W0,
                                              const float* __restrict__ W1,
                                              const float* __restrict__ W2,
                                              u16_t* __restrict__ xb,
                                              u16_t* __restrict__ Wt) {
  __shared__ u16_t T[64][65];
  int bx = blockIdx.x, t = threadIdx.x;
  if (bx < 4096) {
    int i = bx * 256 + t;
    float4 f = ((const float4*)x)[i];
    bf16x4 o = {(__bf16)f.x, (__bf16)f.y, (__bf16)f.z, (__bf16)f.w};
    *(bf16x4*)&xb[(size_t)i * 4] = o;
    return;
  }
  int j = bx - 4096;
  int nx = j & 15, ny = (j >> 4) & 15, z = j >> 8;
  const float* W = z == 0 ? W0 : (z == 1 ? W1 : W2);
  int k0 = ny * 64, n0 = nx * 64;
#pragma unroll
  for (int i = 0; i < 16; i++) {
    int e = i * 256 + t, r = e >> 6, c = e & 63;
    __bf16 hv = (__bf16)W[(size_t)(k0 + r) * 1024 + n0 + c];
    T[r][c] = *(u16_t*)&hv;
  }
  __syncthreads();
  size_t base = ((size_t)z * 1024 + n0) * 1024 + k0;
#pragma unroll
  for (int i = 0; i < 16; i++) {
    int e = i * 256 + t, r = e >> 6, c = e & 63;
    Wt[base + (size_t)r * 1024 + c] = T[c][r];
  }
}

// ---------------- kernel 2: fused QKV GEMM, 256x192 tile, 8-wave, 4-phase/K-tile ----------------
// Round-7: grid 192 -> 256 (BN=192, 16x16 tiles, exactly 1 block/CU on all 256 CUs;
// was 25% CUs idle). 4-phase k-half skeleton UNCHANGED (same barriers/publish points).
// B staging (192 rows): 1 full call + 1 if(wv<4) call (cp16 is per-wave -> wave-uniform
// predication legal). vmcnt counts are wave-asymmetric (heavy 4/half, light 3/half);
// counted waits use the light count (WAITV(6)@P1, WAITV(3)@P3/prologue): exact for
// light waves, conservative (+1-2 loads) for heavy -- safe by vmcnt semantics.
// Epilogue: mat = gn>>10 per fragment; fragments are 16-wide, 1024%16==0 -> no
// fragment straddles a Q/K/V boundary. LDS 112 KB (A 64 + B 48).
__global__ __launch_bounds__(512, 2) void k_gemm_qkv(
    const u16_t* __restrict__ A, const u16_t* __restrict__ Bt,
    const float* __restrict__ bq, const float* __restrict__ bk,
    const float* __restrict__ bv,
    u16_t* __restrict__ Qo, u16_t* __restrict__ Ko, u16_t* __restrict__ Vo) {
  __shared__ u16_t smem[57344];          // 112 KB
  u16_t* As = smem;                      // [buf:16384][half:8192][row*32 + chunk*8], 256 rows
  u16_t* Bs = smem + 32768;              // [buf:12288][half:6144][row*32 + chunk*8], 192 rows

  const int tid = threadIdx.x, lane = tid & 63, wv = tid >> 6;
  const int quad = lane >> 4, col = lane & 15;
  const int wm = wv >> 2, wn = wv & 3;   // 2x4 wave grid; wave owns 128x48 of C

  // XCD swizzle: 256 blocks, 32 consecutive wg per XCD
  int bid = blockIdx.x;
  int wg = (bid & 7) * 32 + (bid >> 3);
  const int tn = (wg & 15) * 192, tm = (wg >> 4) << 8;

  const int r16 = lane >> 2, c4 = lane & 3;
  const int srow = wv * 16 + r16;                    // 0..127 (+128 for second call)
  const int skoff = ((c4 ^ ((r16 >> 1) & 3)) << 3);  // pre-swizzled source chunk (u16)
  const int sdst = srow * 32 + (c4 << 3);            // == wave_base + lane*16B
  const size_t gA0 = (size_t)(tm + srow) * 1024 + skoff;
  const size_t gB0 = (size_t)(tn + srow) * 1024 + skoff;

  f32x4 acc[8][3] = {};

#define STAGE(kt, h, b) do {                                     \
    int dA_ = (b) * 16384 + (h) * 8192 + sdst;                   \
    int dB_ = (b) * 12288 + (h) * 6144 + sdst;                   \
    size_t s_ = (size_t)(kt) * 64 + (h) * 32;                    \
    cp16(A + gA0 + s_, As + dA_);                                \
    cp16(A + gA0 + s_ + (size_t)128 * 1024, As + dA_ + 4096);    \
    cp16(Bt + gB0 + s_, Bs + dB_);                               \
    if (wv < 4)                                                  \
      cp16(Bt + gB0 + s_ + (size_t)128 * 1024, Bs + dB_ + 4096); \
  } while (0)

#define BAR()    asm volatile("s_barrier" ::: "memory")
#define WAITV(N) asm volatile("s_waitcnt vmcnt(" #N ")" ::: "memory")
#define WAITL()  asm volatile("s_waitcnt lgkmcnt(0)" ::: "memory")
#define SCHED0() __builtin_amdgcn_sched_barrier(0)

  STAGE(0, 0, 0);
  STAGE(0, 1, 0);
  WAITV(3);   // publish h0 (h1 stays in flight; light-wave exact, heavy conservative)
  BAR();

  // read-side swizzle: read rows are 16*frag+col (A) / 48wn+16nt+col (B); both have
  // (row>>1)&3 == (col>>1)&3 since the non-col part is 0 mod 8
  const int swz8 = (((lane >> 4) ^ ((col >> 1) & 3)) << 3);
  const int abase = (wm * 128 + col) * 32 + swz8;
  const int bbase = (wn * 48 + col) * 32 + swz8;

  for (int t = 0; t < 16; ++t) {
    const int cur = t & 1, nxt = cur ^ 1;
    const u16_t* Ap = As + cur * 16384;
    const u16_t* Bp = Bs + cur * 12288;
    bf16x8 af[4], bf[3];

    // ---- P0: ks=0, mt 0-3 ----
#pragma unroll
    for (int i = 0; i < 4; i++) af[i] = *(const bf16x8*)&Ap[abase + i * 512];
#pragma unroll
    for (int j = 0; j < 3; j++) bf[j] = *(const bf16x8*)&Bp[bbase + j * 512];
    if (t + 1 < 16) STAGE(t + 1, 0, nxt);
    BAR(); WAITL(); SCHED0();
    __builtin_amdgcn_s_setprio(1);
#pragma unroll
    for (int i = 0; i < 4; i++)
#pragma unroll
      for (int j = 0; j < 3; j++) acc[i][j] = MFMA(af[i], bf[j], acc[i][j]);
    __builtin_amdgcn_s_setprio(0);
    BAR();

    // ---- P1: ks=0, mt 4-7 (reuse bf) ----
#pragma unroll
    for (int i = 0; i < 4; i++) af[i] = *(const bf16x8*)&Ap[abase + (i + 4) * 512];
    if (t + 1 < 16) { STAGE(t + 1, 1, nxt); WAITV(6); }  // publish (t,h1)
    else            { WAITV(0); }                        // final tile: drain h1
    BAR(); WAITL(); SCHED0();
    __builtin_amdgcn_s_setprio(1);
#pragma unroll
    for (int i = 0; i < 4; i++)
#pragma unroll
      for (int j = 0; j < 3; j++) acc[i + 4][j] = MFMA(af[i], bf[j], acc[i + 4][j]);
    __builtin_amdgcn_s_setprio(0);
    BAR();

    // ---- P2: ks=1, mt 0-3 ----
#pragma unroll
    for (int i = 0; i < 4; i++) af[i] = *(const bf16x8*)&Ap[8192 + abase + i * 512];
#pragma unroll
    for (int j = 0; j < 3; j++) bf[j] = *(const bf16x8*)&Bp[6144 + bbase + j * 512];
    BAR(); WAITL(); SCHED0();
    __builtin_amdgcn_s_setprio(1);
#pragma unroll
    for (int i = 0; i < 4; i++)
#pragma unroll
      for (int j = 0; j < 3; j++) acc[i][j] = MFMA(af[i], bf[j], acc[i][j]);
    __builtin_amdgcn_s_setprio(0);
    BAR();

    // ---- P3: ks=1, mt 4-7 ----
#pragma unroll
    for (int i = 0; i < 4; i++) af[i] = *(const bf16x8*)&Ap[8192 + abase + (i + 4) * 512];
    if (t + 1 < 16) WAITV(3);   // publish (t+1,h0); (t+1,h1) stays in flight
    WAITL();                    // reads of cur buf done before bar (overwrite hazard)
    BAR(); SCHED0();
    __builtin_amdgcn_s_setprio(1);
#pragma unroll
    for (int i = 0; i < 4; i++)
#pragma unroll
      for (int j = 0; j < 3; j++) acc[i + 4][j] = MFMA(af[i], bf[j], acc[i + 4][j]);
    __builtin_amdgcn_s_setprio(0);
    BAR();
  }

#undef STAGE

  // epilogue: per-(wn,nt) fragment mat select (tile can span Q|K|V boundaries)
#pragma unroll
  for (int nt = 0; nt < 3; nt++) {
    int gn = tn + wn * 48 + nt * 16 + col;
    int mat = gn >> 10, d = gn & 1023, h = d >> 6, dk = d & 63;
    const float* bias = mat == 0 ? bq : (mat == 1 ? bk : bv);
    float bb = bias[d];
    if (mat == 2) {
#pragma unroll
      for (int mt = 0; mt < 8; mt++) {
        int gm = tm + wm * 128 + mt * 16 + quad * 4;
        int b = gm >> 11, s = gm & 2047;
        bf16x4 pk4;
#pragma unroll
        for (int r = 0; r < 4; r++) pk4[r] = (__bf16)(acc[mt][nt][r] + bb);
        *(bf16x4*)&Vo[((size_t)((b * 16 + h) * 64 + dk)) * 2048 + s] = pk4;
      }
    } else {
      u16_t* O = mat == 0 ? Qo : Ko;
      const float scl = mat == 0 ? 0.18033688011112042f : 1.0f;  // log2(e)/8 in Q
#pragma unroll
      for (int mt = 0; mt < 8; mt++) {
#pragma unroll
        for (int r = 0; r < 4; r++) {
          int gm = tm + wm * 128 + mt * 16 + quad * 4 + r;
          int b = gm >> 11, s = gm & 2047;
          __bf16 hv = (__bf16)((acc[mt][nt][r] + bb) * scl);
          O[((size_t)((b * 16 + h) * 2048 + s)) * 64 + dk] = *(u16_t*)&hv;
        }
      }
    }
  }
}

// ---------------- kernel 3: fused attention (v11, unchanged) ----------------
__global__ __launch_bounds__(256, 4) void k_attn(const u16_t* __restrict__ Q,
                                                 const u16_t* __restrict__ K,
                                                 const u16_t* __restrict__ Vt,
                                                 float* __restrict__ out) {
  __shared__ u16_t smem[20480];        // 40 KB
  u16_t* Qs  = smem;                   // 8 KB: Q staging (then reduction buffer)
  u16_t* Ksb = smem + 4096;            // 16 KB dbuf: K tiles [64k][64d]
  u16_t* Vsb = smem + 12288;           // 16 KB dbuf: V^T tiles [64d][64k]
  const int tid = threadIdx.x, lane = tid & 63, wv = tid >> 6;
  const int quad = lane >> 4, col = lane & 15;
  const int qh = wv >> 1, kh = wv & 1;

  // XCD swizzle: bid&7 = XCD, 4 heads per XCD -> K/V (2 MB) fit 4 MB L2
  const int bid = blockIdx.x;
  const int bh = (bid & 7) + 8 * ((bid >> 3) >> 5);
  const int qt = (bid >> 3) & 31;
  const int b = bh >> 4, h = bh & 15;
  const int r8 = lane >> 3, c8 = lane & 7;

  const u16_t* Qg = Q + ((size_t)bh * 2048 + qt * 64) * 64;
  const u16_t* Kg = K + (size_t)bh * 2048 * 64;
  const u16_t* Vg = Vt + (size_t)bh * 64 * 2048;

  // staging geometry (hoisted): two cp16 per array per step
  const int lch  = c8 ^ r8;
  const int row0 = (wv * 2) * 8 + r8, row1 = (wv * 2 + 1) * 8 + r8;
  const int ldst0 = (wv * 2) * 512 + lane * 8;
  const int ldst1 = (wv * 2 + 1) * 512 + lane * 8;
  const int gk0 = row0 * 64 + lch * 8,   gk1 = row1 * 64 + lch * 8;
  const int gv0 = row0 * 2048 + lch * 8, gv1 = row1 * 2048 + lch * 8;

  // prologue staging: Q + K0 only (V0 staged inside step kt=0)
  cp16(Qg + gk0, Qs + ldst0);
  cp16(Qg + gk1, Qs + ldst1);
  cp16(Kg + gk0, Ksb + ldst0);
  cp16(Kg + gk1, Ksb + ldst1);
  __syncthreads();

  // Q fragments (this wave's 32 q) -> registers
  bf16x8 qf[2][2];
#pragma unroll
  for (int nt = 0; nt < 2; nt++)
#pragma unroll
    for (int ks = 0; ks < 2; ks++) {
      int row = qh * 32 + nt * 16 + col;
      qf[nt][ks] = *(const bf16x8*)&Qs[row * 64 + (((ks * 4 + quad) ^ (row & 7)) * 8)];
    }

  // hoisted fragment addresses (all loop-invariant)
  int ka[2][2];
#pragma unroll
  for (int ks = 0; ks < 2; ks++)
#pragma unroll
    for (int mt = 0; mt < 2; mt++) {
      int row = kh * 32 + mt * 16 + col;
      ka[ks][mt] = row * 64 + (((ks * 4 + quad) ^ (row & 7)) * 8);
    }
  int va0[4], va1[4];
#pragma unroll
  for (int dt = 0; dt < 4; dt++) {
    int row = dt * 16 + col;
    int cc = kh * 4 + (quad >> 1);
    va0[dt] = row * 64 + ((cc ^ (row & 7)) * 8) + (quad & 1) * 4;
    va1[dt] = row * 64 + (((cc + 2) ^ (row & 7)) * 8) + (quad & 1) * 4;
  }

  const short one_bf = (short)0x3F80;  // bf16 1.0
  s16x8 ones8s = {one_bf, one_bf, one_bf, one_bf, one_bf, one_bf, one_bf, one_bf};
  const bf16x8 ones8 = *(bf16x8*)&ones8s;
  const f32x4 z4 = {0.f, 0.f, 0.f, 0.f};

  f32x4 ao[2][4] = {};
  f32x4 dn[2] = {};
  s16x8 pA[2] = {}, pB[2] = {};   // P as s16x8 per nt, elem = mt*4+r

  // one pipeline step: stage K(KT+1)->Ksb[CUR^1], V(KT)->Vsb[CUR];
  // QK^T(KT) from Ksb[CUR]; PV(KT-1) from Vsb[CUR^1] with PFR (K=32); exp -> PFW.
#define ATTN_STEP(KT, CUR, PFW, PFR, DO_PV, DO_PRE) do {                              \
    const u16_t* Kc = Ksb + (CUR) * 4096;                                             \
    const u16_t* Vp = Vsb + ((CUR) ^ 1) * 4096;                                       \
    u16_t* Kn = Ksb + ((CUR) ^ 1) * 4096;                                             \
    u16_t* Vn = Vsb + (CUR) * 4096;                                                   \
    if (DO_PRE) {                                                                     \
      const u16_t* kb = Kg + (size_t)((KT) + 1) * 4096;                               \
      cp16(kb + gk0, Kn + ldst0);                                                     \
      cp16(kb + gk1, Kn + ldst1);                                                     \
    }                                                                                 \
    {                                                                                 \
      const u16_t* vb = Vg + (size_t)(KT) * 64;                                       \
      cp16(vb + gv0, Vn + ldst0);                                                     \
      cp16(vb + gv1, Vn + ldst1);                                                     \
    }                                                                                 \
    f32x4 sc[2][2];                                                                   \
    __builtin_amdgcn_s_setprio(1);                                                    \
    {                                                                                 \
      bf16x8 kf0 = *(const bf16x8*)&Kc[ka[0][0]];                                     \
      bf16x8 kf1 = *(const bf16x8*)&Kc[ka[0][1]];                                     \
      sc[0][0] = MFMA(kf0, qf[0][0], z4);                                             \
      sc[0][1] = MFMA(kf0, qf[1][0], z4);                                             \
      sc[1][0] = MFMA(kf1, qf[0][0], z4);                                             \
      sc[1][1] = MFMA(kf1, qf[1][0], z4);                                             \
      kf0 = *(const bf16x8*)&Kc[ka[1][0]];                                            \
      kf1 = *(const bf16x8*)&Kc[ka[1][1]];                                            \
      sc[0][0] = MFMA(kf0, qf[0][1], sc[0][0]);                                       \
      sc[0][1] = MFMA(kf0, qf[1][1], sc[0][1]);                                       \
      sc[1][0] = MFMA(kf1, qf[0][1], sc[1][0]);                                       \
      sc[1][1] = MFMA(kf1, qf[1][1], sc[1][1]);                                       \
    }                                                                                 \
    if (DO_PV) {                                                                      \
      bf16x8 pa0 = b8(PFR[0]);                                                        \
      bf16x8 pa1 = b8(PFR[1]);                                                        \
      _Pragma("unroll")                                                               \
      for (int dt = 0; dt < 4; dt++) {                                                \
        bf16x8 vv = cat8(*(const s16x4*)&Vp[va0[dt]], *(const s16x4*)&Vp[va1[dt]]);   \
        ao[0][dt] = MFMA(pa0, vv, ao[0][dt]);                                         \
        ao[1][dt] = MFMA(pa1, vv, ao[1][dt]);                                         \
      }                                                                               \
    }                                                                                 \
    __builtin_amdgcn_s_setprio(0);                                                    \
    _Pragma("unroll")                                                                 \
    for (int mt = 0; mt < 2; mt++)                                                    \
      _Pragma("unroll")                                                               \
      for (int nt = 0; nt < 2; nt++)                                                  \
        _Pragma("unroll")                                                             \
        for (int r = 0; r < 4; r++) {                                                 \
          __bf16 e = (__bf16)__builtin_amdgcn_exp2f(sc[mt][nt][r]);                   \
          PFW[nt][mt * 4 + r] = *(short*)&e;                                          \
        }                                                                             \
    dn[0] = MFMA(b8(PFW[0]), ones8, dn[0]);                                           \
    dn[1] = MFMA(b8(PFW[1]), ones8, dn[1]);                                           \
    __syncthreads();                                                                  \
  } while (0)

  // peeled: kt=0 (no PV), kt=1; main loop kt=2..29; peeled kt=30, kt=31 (no K prefetch)
  ATTN_STEP(0, 0, pA, pB, 0, 1);
  ATTN_STEP(1, 1, pB, pA, 1, 1);
#pragma unroll 1
  for (int kt2 = 1; kt2 < 15; kt2++) {
    int kt0 = kt2 * 2;
    ATTN_STEP(kt0,     0, pA, pB, 1, 1);
    ATTN_STEP(kt0 + 1, 1, pB, pA, 1, 1);
  }
  ATTN_STEP(30, 0, pA, pB, 1, 1);
  ATTN_STEP(31, 1, pB, pA, 1, 0);
#undef ATTN_STEP

  // epilogue PV: P(31) is in pB, V(31) in Vsb buffer 1 (published by last barrier)
  {
    const u16_t* Vp = Vsb + 4096;
    bf16x8 pa0 = b8(pB[0]);
    bf16x8 pa1 = b8(pB[1]);
#pragma unroll
    for (int dt = 0; dt < 4; dt++) {
      bf16x8 vv = cat8(*(const s16x4*)&Vp[va0[dt]], *(const s16x4*)&Vp[va1[dt]]);
      ao[0][dt] = MFMA(pa0, vv, ao[0][dt]);
      ao[1][dt] = MFMA(pa1, vv, ao[1][dt]);
    }
  }

  // cross-wave merge over kh: kh=1 dumps partials, kh=0 adds + normalizes + stores
  float* red = (float*)(smem + 4096);  // K/V region dead now
  const int rb = (qh * 64 + lane) * 41;
  if (kh == 1) {
#pragma unroll
    for (int nt = 0; nt < 2; nt++) {
#pragma unroll
      for (int dt = 0; dt < 4; dt++)
#pragma unroll
        for (int r = 0; r < 4; r++)
          red[rb + (nt * 4 + dt) * 4 + r] = ao[nt][dt][r];
#pragma unroll
      for (int r = 0; r < 4; r++)
        red[rb + 32 + nt * 4 + r] = dn[nt][r];
    }
  }
  __syncthreads();
  if (kh == 0) {
#pragma unroll
    for (int nt = 0; nt < 2; nt++) {
      float inv[4];
#pragma unroll
      for (int r = 0; r < 4; r++)
        inv[r] = 1.0f / (dn[nt][r] + red[rb + 32 + nt * 4 + r] + 1e-8f);
#pragma unroll
      for (int dt = 0; dt < 4; dt++) {
#pragma unroll
        for (int r = 0; r < 4; r++) {
          float v = (ao[nt][dt][r] + red[rb + (nt * 4 + dt) * 4 + r]) * inv[r];
          int s = qt * 64 + qh * 32 + nt * 16 + quad * 4 + r;
          out[((size_t)b * 2048 + s) * 1024 + h * 64 + dt * 16 + col] = v;
        }
      }
    }
  }
}

// ---------------- launcher ----------------
extern "C" void kernel_launch(void* const* d_in, const int* in_sizes, int n_in,
                              void* d_out, int out_size, void* d_ws, size_t ws_size,
                              hipStream_t stream) {
  const float* x  = (const float*)d_in[0];
  const float* Wq = (const float*)d_in[1];
  const float* bq = (const float*)d_in[2];
  const float* Wk = (const float*)d_in[3];
  const float* bk = (const float*)d_in[4];
  const float* Wv = (const float*)d_in[5];
  const float* bv = (const float*)d_in[6];
  float* out = (float*)d_out;

  char* ws = (char*)d_ws;
  u16_t* xb  = (u16_t*)(ws);                 // 8 MB   x bf16 [4096][1024]
  u16_t* Wt  = (u16_t*)(ws + 8388608);       // 6 MB   Wt bf16 [3072][1024]
  u16_t* Qb  = (u16_t*)(ws + 14680064);      // 8 MB   Q bf16 [bh][s][dk] (pre-scaled)
  u16_t* Kb  = (u16_t*)(ws + 23068672);      // 8 MB   K bf16 [bh][s][dk]
  u16_t* Vtb = (u16_t*)(ws + 31457280);      // 8 MB   V^T bf16 [bh][dk][s]

  hipLaunchKernelGGL(k_prep, dim3(4864), dim3(256), 0, stream, x, Wq, Wk, Wv, xb, Wt);
  hipLaunchKernelGGL(k_gemm_qkv, dim3(256), dim3(512), 0, stream,
                     xb, Wt, bq, bk, bv, Qb, Kb, Vtb);
  hipLaunchKernelGGL(k_attn, dim3(1024), dim3(256), 0, stream, Qb, Kb, Vtb, out);
}

// Round 9
// 159.932 us; speedup vs baseline: 1.0936x; 1.0492x over previous
//
#include <hip/hip_runtime.h>
#include <hip/hip_bf16.h>
#include <stdint.h>

typedef __bf16 bf16x8 __attribute__((ext_vector_type(8)));
typedef __bf16 bf16x4 __attribute__((ext_vector_type(4)));
typedef float  f32x4  __attribute__((ext_vector_type(4)));
typedef short  s16x4  __attribute__((ext_vector_type(4)));
typedef short  s16x8  __attribute__((ext_vector_type(8)));
typedef unsigned short u16_t;

#define MFMA(a, b, c)   __builtin_amdgcn_mfma_f32_16x16x32_bf16((a), (b), (c), 0, 0, 0)

// concat two s16x4 halves into a bf16x8 MFMA operand
__device__ __forceinline__ bf16x8 cat8(s16x4 a, s16x4 b) {
  s16x8 t = __builtin_shufflevector(a, b, 0, 1, 2, 3, 4, 5, 6, 7);
  return *(bf16x8*)&t;
}
__device__ __forceinline__ bf16x8 b8(s16x8 v) {
  bf16x8 r; __builtin_memcpy(&r, &v, 16); return r;
}

// async global->LDS, 16B per lane; LDS dest is wave-uniform base + lane*16
__device__ __forceinline__ void cp16(const void* g, void* l) {
  __builtin_amdgcn_global_load_lds(
      (const __attribute__((address_space(1))) unsigned int*)g,
      (__attribute__((address_space(3))) unsigned int*)l, 16, 0, 0);
}

// ---------------- kernel 1: fused x-convert + W-transpose-convert ----------------
__global__ __launch_bounds__(256) void k_prep(const float* __restrict__ x,
                                              const float* __restrict__ W0,
                                              const float* __restrict__ W1,
                                              const float* __restrict__ W2,
                                              u16_t* __restrict__ xb,
                                              u16_t* __restrict__ Wt) {
  __shared__ u16_t T[64][65];
  int bx = blockIdx.x, t = threadIdx.x;
  if (bx < 4096) {
    int i = bx * 256 + t;
    float4 f = ((const float4*)x)[i];
    bf16x4 o = {(__bf16)f.x, (__bf16)f.y, (__bf16)f.z, (__bf16)f.w};
    *(bf16x4*)&xb[(size_t)i * 4] = o;
    return;
  }
  int j = bx - 4096;
  int nx = j & 15, ny = (j >> 4) & 15, z = j >> 8;
  const float* W = z == 0 ? W0 : (z == 1 ? W1 : W2);
  int k0 = ny * 64, n0 = nx * 64;
#pragma unroll
  for (int i = 0; i < 16; i++) {
    int e = i * 256 + t, r = e >> 6, c = e & 63;
    __bf16 hv = (__bf16)W[(size_t)(k0 + r) * 1024 + n0 + c];
    T[r][c] = *(u16_t*)&hv;
  }
  __syncthreads();
  size_t base = ((size_t)z * 1024 + n0) * 1024 + k0;
#pragma unroll
  for (int i = 0; i < 16; i++) {
    int e = i * 256 + t, r = e >> 6, c = e & 63;
    Wt[base + (size_t)r * 1024 + c] = T[c][r];
  }
}

// ---------------- kernel 2: fused QKV GEMM, 256x192 tile, 8-wave, 4-phase/K-tile ----------------
// (round-7 version, kept: correct, ~neutral-to-slightly-better; not iterating blind.)
__global__ __launch_bounds__(512, 2) void k_gemm_qkv(
    const u16_t* __restrict__ A, const u16_t* __restrict__ Bt,
    const float* __restrict__ bq, const float* __restrict__ bk,
    const float* __restrict__ bv,
    u16_t* __restrict__ Qo, u16_t* __restrict__ Ko, u16_t* __restrict__ Vo) {
  __shared__ u16_t smem[57344];          // 112 KB
  u16_t* As = smem;                      // [buf:16384][half:8192][row*32 + chunk*8], 256 rows
  u16_t* Bs = smem + 32768;              // [buf:12288][half:6144][row*32 + chunk*8], 192 rows

  const int tid = threadIdx.x, lane = tid & 63, wv = tid >> 6;
  const int quad = lane >> 4, col = lane & 15;
  const int wm = wv >> 2, wn = wv & 3;   // 2x4 wave grid; wave owns 128x48 of C

  // XCD swizzle: 256 blocks, 32 consecutive wg per XCD
  int bid = blockIdx.x;
  int wg = (bid & 7) * 32 + (bid >> 3);
  const int tn = (wg & 15) * 192, tm = (wg >> 4) << 8;

  const int r16 = lane >> 2, c4 = lane & 3;
  const int srow = wv * 16 + r16;                    // 0..127 (+128 for second call)
  const int skoff = ((c4 ^ ((r16 >> 1) & 3)) << 3);  // pre-swizzled source chunk (u16)
  const int sdst = srow * 32 + (c4 << 3);            // == wave_base + lane*16B
  const size_t gA0 = (size_t)(tm + srow) * 1024 + skoff;
  const size_t gB0 = (size_t)(tn + srow) * 1024 + skoff;

  f32x4 acc[8][3] = {};

#define STAGE(kt, h, b) do {                                     \
    int dA_ = (b) * 16384 + (h) * 8192 + sdst;                   \
    int dB_ = (b) * 12288 + (h) * 6144 + sdst;                   \
    size_t s_ = (size_t)(kt) * 64 + (h) * 32;                    \
    cp16(A + gA0 + s_, As + dA_);                                \
    cp16(A + gA0 + s_ + (size_t)128 * 1024, As + dA_ + 4096);    \
    cp16(Bt + gB0 + s_, Bs + dB_);                               \
    if (wv < 4)                                                  \
      cp16(Bt + gB0 + s_ + (size_t)128 * 1024, Bs + dB_ + 4096); \
  } while (0)

#define BAR()    asm volatile("s_barrier" ::: "memory")
#define WAITV(N) asm volatile("s_waitcnt vmcnt(" #N ")" ::: "memory")
#define WAITL()  asm volatile("s_waitcnt lgkmcnt(0)" ::: "memory")
#define SCHED0() __builtin_amdgcn_sched_barrier(0)

  STAGE(0, 0, 0);
  STAGE(0, 1, 0);
  WAITV(3);   // publish h0 (light-wave exact, heavy conservative)
  BAR();

  const int swz8 = (((lane >> 4) ^ ((col >> 1) & 3)) << 3);
  const int abase = (wm * 128 + col) * 32 + swz8;
  const int bbase = (wn * 48 + col) * 32 + swz8;

  for (int t = 0; t < 16; ++t) {
    const int cur = t & 1, nxt = cur ^ 1;
    const u16_t* Ap = As + cur * 16384;
    const u16_t* Bp = Bs + cur * 12288;
    bf16x8 af[4], bf[3];

    // ---- P0: ks=0, mt 0-3 ----
#pragma unroll
    for (int i = 0; i < 4; i++) af[i] = *(const bf16x8*)&Ap[abase + i * 512];
#pragma unroll
    for (int j = 0; j < 3; j++) bf[j] = *(const bf16x8*)&Bp[bbase + j * 512];
    if (t + 1 < 16) STAGE(t + 1, 0, nxt);
    BAR(); WAITL(); SCHED0();
    __builtin_amdgcn_s_setprio(1);
#pragma unroll
    for (int i = 0; i < 4; i++)
#pragma unroll
      for (int j = 0; j < 3; j++) acc[i][j] = MFMA(af[i], bf[j], acc[i][j]);
    __builtin_amdgcn_s_setprio(0);
    BAR();

    // ---- P1: ks=0, mt 4-7 (reuse bf) ----
#pragma unroll
    for (int i = 0; i < 4; i++) af[i] = *(const bf16x8*)&Ap[abase + (i + 4) * 512];
    if (t + 1 < 16) { STAGE(t + 1, 1, nxt); WAITV(6); }  // publish (t,h1)
    else            { WAITV(0); }                        // final tile: drain h1
    BAR(); WAITL(); SCHED0();
    __builtin_amdgcn_s_setprio(1);
#pragma unroll
    for (int i = 0; i < 4; i++)
#pragma unroll
      for (int j = 0; j < 3; j++) acc[i + 4][j] = MFMA(af[i], bf[j], acc[i + 4][j]);
    __builtin_amdgcn_s_setprio(0);
    BAR();

    // ---- P2: ks=1, mt 0-3 ----
#pragma unroll
    for (int i = 0; i < 4; i++) af[i] = *(const bf16x8*)&Ap[8192 + abase + i * 512];
#pragma unroll
    for (int j = 0; j < 3; j++) bf[j] = *(const bf16x8*)&Bp[6144 + bbase + j * 512];
    BAR(); WAITL(); SCHED0();
    __builtin_amdgcn_s_setprio(1);
#pragma unroll
    for (int i = 0; i < 4; i++)
#pragma unroll
      for (int j = 0; j < 3; j++) acc[i][j] = MFMA(af[i], bf[j], acc[i][j]);
    __builtin_amdgcn_s_setprio(0);
    BAR();

    // ---- P3: ks=1, mt 4-7 ----
#pragma unroll
    for (int i = 0; i < 4; i++) af[i] = *(const bf16x8*)&Ap[8192 + abase + (i + 4) * 512];
    if (t + 1 < 16) WAITV(3);   // publish (t+1,h0)
    WAITL();                    // reads of cur buf done before bar
    BAR(); SCHED0();
    __builtin_amdgcn_s_setprio(1);
#pragma unroll
    for (int i = 0; i < 4; i++)
#pragma unroll
      for (int j = 0; j < 3; j++) acc[i + 4][j] = MFMA(af[i], bf[j], acc[i + 4][j]);
    __builtin_amdgcn_s_setprio(0);
    BAR();
  }

#undef STAGE

  // epilogue: per-(wn,nt) fragment mat select (tile can span Q|K|V boundaries)
#pragma unroll
  for (int nt = 0; nt < 3; nt++) {
    int gn = tn + wn * 48 + nt * 16 + col;
    int mat = gn >> 10, d = gn & 1023, h = d >> 6, dk = d & 63;
    const float* bias = mat == 0 ? bq : (mat == 1 ? bk : bv);
    float bb = bias[d];
    if (mat == 2) {
#pragma unroll
      for (int mt = 0; mt < 8; mt++) {
        int gm = tm + wm * 128 + mt * 16 + quad * 4;
        int b = gm >> 11, s = gm & 2047;
        bf16x4 pk4;
#pragma unroll
        for (int r = 0; r < 4; r++) pk4[r] = (__bf16)(acc[mt][nt][r] + bb);
        *(bf16x4*)&Vo[((size_t)((b * 16 + h) * 64 + dk)) * 2048 + s] = pk4;
      }
    } else {
      u16_t* O = mat == 0 ? Qo : Ko;
      const float scl = mat == 0 ? 0.18033688011112042f : 1.0f;  // log2(e)/8 in Q
#pragma unroll
      for (int mt = 0; mt < 8; mt++) {
#pragma unroll
        for (int r = 0; r < 4; r++) {
          int gm = tm + wm * 128 + mt * 16 + quad * 4 + r;
          int b = gm >> 11, s = gm & 2047;
          __bf16 hv = (__bf16)((acc[mt][nt][r] + bb) * scl);
          O[((size_t)((b * 16 + h) * 2048 + s)) * 64 + dk] = *(u16_t*)&hv;
        }
      }
    }
  }
}

// ---------------- kernel 3: fused attention (v12 = QBLK 64 -> 128) ----------------
// 4 waves, each owns 32 FULL q-rows (no kh key-split, no cross-wave reduction).
// Per 64-key step/wave: 16 QK^T + 16 PV + 4 dn MFMA (was 8+8+2) against the SAME
// staging (4 cp16) + 2 barriers + drain -> staging/barrier/drain per unit work
// halved; K/V HBM traffic halved. kh -> g (key-group 0/1) in the verified P/V slot
// mapping; mt extends 2->4. T15 delayed-PV and dbuf scheme unchanged.
// LDS 48KB (Q 16 + K dbuf 16 + V dbuf 16); grid 512 = 2 blocks/CU.
__global__ __launch_bounds__(256, 2) void k_attn(const u16_t* __restrict__ Q,
                                                 const u16_t* __restrict__ K,
                                                 const u16_t* __restrict__ Vt,
                                                 float* __restrict__ out) {
  __shared__ u16_t smem[24576];        // 48 KB
  u16_t* Qs  = smem;                   // 16 KB: Q staging [128][64]
  u16_t* Ksb = smem + 8192;            // 16 KB dbuf: K tiles [64k][64d]
  u16_t* Vsb = smem + 16384;           // 16 KB dbuf: V^T tiles [64d][64k]
  const int tid = threadIdx.x, lane = tid & 63, wv = tid >> 6;
  const int quad = lane >> 4, col = lane & 15;

  // XCD swizzle: bid&7 = XCD; per XCD: 4 head-groups x 16 qt -> K/V (2 MB) fit 4 MB L2
  const int bid = blockIdx.x;
  const int bh = (bid & 7) + 8 * ((bid >> 3) >> 4);
  const int qt = (bid >> 3) & 15;
  const int b = bh >> 4, h = bh & 15;
  const int r8 = lane >> 3, c8 = lane & 7;

  const u16_t* Qg = Q + ((size_t)bh * 2048 + qt * 128) * 64;
  const u16_t* Kg = K + (size_t)bh * 2048 * 64;
  const u16_t* Vg = Vt + (size_t)bh * 64 * 2048;

  // staging geometry (hoisted): K/V = 8 chunks of 8 rows, 2 per wave
  const int lch  = c8 ^ r8;
  const int row0 = (wv * 2) * 8 + r8, row1 = (wv * 2 + 1) * 8 + r8;
  const int ldst0 = (wv * 2) * 512 + lane * 8;
  const int ldst1 = (wv * 2 + 1) * 512 + lane * 8;
  const int gk0 = row0 * 64 + lch * 8,   gk1 = row1 * 64 + lch * 8;
  const int gv0 = row0 * 2048 + lch * 8, gv1 = row1 * 2048 + lch * 8;

  // prologue: Q (16 chunks, 4/wave) + K0
#pragma unroll
  for (int i = 0; i < 4; i++) {
    int c = wv * 4 + i;
    cp16(Qg + (c * 8 + r8) * 64 + lch * 8, Qs + c * 512 + lane * 8);
  }
  cp16(Kg + gk0, Ksb + ldst0);
  cp16(Kg + gk1, Ksb + ldst1);
  __syncthreads();

  // Q fragments (this wave's 32 q = rows wv*32..wv*32+31) -> registers
  bf16x8 qf[2][2];
#pragma unroll
  for (int nt = 0; nt < 2; nt++)
#pragma unroll
    for (int ks = 0; ks < 2; ks++) {
      int row = wv * 32 + nt * 16 + col;
      qf[nt][ks] = *(const bf16x8*)&Qs[row * 64 + (((ks * 4 + quad) ^ (row & 7)) * 8)];
    }

  // hoisted fragment addresses (loop-invariant)
  int ka[2][4];
#pragma unroll
  for (int ks = 0; ks < 2; ks++)
#pragma unroll
    for (int mt = 0; mt < 4; mt++) {
      int row = mt * 16 + col;
      ka[ks][mt] = row * 64 + (((ks * 4 + quad) ^ (row & 7)) * 8);
    }
  int va0[2][4], va1[2][4];
#pragma unroll
  for (int g = 0; g < 2; g++)
#pragma unroll
    for (int dt = 0; dt < 4; dt++) {
      int row = dt * 16 + col;
      int cc = g * 4 + (quad >> 1);
      va0[g][dt] = row * 64 + ((cc ^ (row & 7)) * 8) + (quad & 1) * 4;
      va1[g][dt] = row * 64 + (((cc + 2) ^ (row & 7)) * 8) + (quad & 1) * 4;
    }

  const short one_bf = (short)0x3F80;  // bf16 1.0
  s16x8 ones8s = {one_bf, one_bf, one_bf, one_bf, one_bf, one_bf, one_bf, one_bf};
  const bf16x8 ones8 = *(bf16x8*)&ones8s;
  const f32x4 z4 = {0.f, 0.f, 0.f, 0.f};

  f32x4 ao[2][4] = {};
  f32x4 dn[2] = {};
  s16x8 pA[2][2] = {}, pB[2][2] = {};   // P[nt][g], elem = (mt&1)*4+r for mt=2g+(mt&1)

#define ATTN_STEP(KT, CUR, PFW, PFR, DO_PV, DO_PRE) do {                              \
    const u16_t* Kc = Ksb + (CUR) * 4096;                                             \
    const u16_t* Vp = Vsb + ((CUR) ^ 1) * 4096;                                       \
    u16_t* Kn = Ksb + ((CUR) ^ 1) * 4096;                                             \
    u16_t* Vn = Vsb + (CUR) * 4096;                                                   \
    if (DO_PRE) {                                                                     \
      const u16_t* kb = Kg + (size_t)((KT) + 1) * 4096;                               \
      cp16(kb + gk0, Kn + ldst0);                                                     \
      cp16(kb + gk1, Kn + ldst1);                                                     \
    }                                                                                 \
    {                                                                                 \
      const u16_t* vb = Vg + (size_t)(KT) * 64;                                       \
      cp16(vb + gv0, Vn + ldst0);                                                     \
      cp16(vb + gv1, Vn + ldst1);                                                     \
    }                                                                                 \
    f32x4 sc[4][2];                                                                   \
    __builtin_amdgcn_s_setprio(1);                                                    \
    _Pragma("unroll")                                                                 \
    for (int ks = 0; ks < 2; ks++) {                                                  \
      bf16x8 kf[4];                                                                   \
      _Pragma("unroll")                                                               \
      for (int mt = 0; mt < 4; mt++) kf[mt] = *(const bf16x8*)&Kc[ka[ks][mt]];        \
      _Pragma("unroll")                                                               \
      for (int mt = 0; mt < 4; mt++)                                                  \
        _Pragma("unroll")                                                             \
        for (int nt = 0; nt < 2; nt++)                                                \
          sc[mt][nt] = ks ? MFMA(kf[mt], qf[nt][1], sc[mt][nt])                       \
                          : MFMA(kf[mt], qf[nt][0], z4);                              \
    }                                                                                 \
    if (DO_PV) {                                                                      \
      bf16x8 pa00 = b8(PFR[0][0]), pa01 = b8(PFR[0][1]);                              \
      bf16x8 pa10 = b8(PFR[1][0]), pa11 = b8(PFR[1][1]);                              \
      _Pragma("unroll")                                                               \
      for (int dt = 0; dt < 4; dt++) {                                                \
        bf16x8 vv0 = cat8(*(const s16x4*)&Vp[va0[0][dt]],                             \
                          *(const s16x4*)&Vp[va1[0][dt]]);                            \
        bf16x8 vv1 = cat8(*(const s16x4*)&Vp[va0[1][dt]],                             \
                          *(const s16x4*)&Vp[va1[1][dt]]);                            \
        ao[0][dt] = MFMA(pa00, vv0, ao[0][dt]);                                       \
        ao[0][dt] = MFMA(pa01, vv1, ao[0][dt]);                                       \
        ao[1][dt] = MFMA(pa10, vv0, ao[1][dt]);                                       \
        ao[1][dt] = MFMA(pa11, vv1, ao[1][dt]);                                       \
      }                                                                               \
    }                                                                                 \
    __builtin_amdgcn_s_setprio(0);                                                    \
    _Pragma("unroll")                                                                 \
    for (int mt = 0; mt < 4; mt++)                                                    \
      _Pragma("unroll")                                                               \
      for (int nt = 0; nt < 2; nt++)                                                  \
        _Pragma("unroll")                                                             \
        for (int r = 0; r < 4; r++) {                                                 \
          __bf16 e = (__bf16)__builtin_amdgcn_exp2f(sc[mt][nt][r]);                   \
          PFW[nt][mt >> 1][(mt & 1) * 4 + r] = *(short*)&e;                           \
        }                                                                             \
    dn[0] = MFMA(b8(PFW[0][0]), ones8, dn[0]);                                        \
    dn[0] = MFMA(b8(PFW[0][1]), ones8, dn[0]);                                        \
    dn[1] = MFMA(b8(PFW[1][0]), ones8, dn[1]);                                        \
    dn[1] = MFMA(b8(PFW[1][1]), ones8, dn[1]);                                        \
    __syncthreads();                                                                  \
  } while (0)

  // peeled: kt=0 (no PV); main loop; kt=31 (no K prefetch); epilogue PV after loop
  ATTN_STEP(0, 0, pA, pB, 0, 1);
  ATTN_STEP(1, 1, pB, pA, 1, 1);
#pragma unroll 1
  for (int kt2 = 1; kt2 < 15; kt2++) {
    int kt0 = kt2 * 2;
    ATTN_STEP(kt0,     0, pA, pB, 1, 1);
    ATTN_STEP(kt0 + 1, 1, pB, pA, 1, 1);
  }
  ATTN_STEP(30, 0, pA, pB, 1, 1);
  ATTN_STEP(31, 1, pB, pA, 1, 0);
#undef ATTN_STEP

  // epilogue PV: P(31) in pB, V(31) in Vsb buffer 1 (published by last barrier)
  {
    const u16_t* Vp = Vsb + 4096;
    bf16x8 pa00 = b8(pB[0][0]), pa01 = b8(pB[0][1]);
    bf16x8 pa10 = b8(pB[1][0]), pa11 = b8(pB[1][1]);
#pragma unroll
    for (int dt = 0; dt < 4; dt++) {
      bf16x8 vv0 = cat8(*(const s16x4*)&Vp[va0[0][dt]], *(const s16x4*)&Vp[va1[0][dt]]);
      bf16x8 vv1 = cat8(*(const s16x4*)&Vp[va0[1][dt]], *(const s16x4*)&Vp[va1[1][dt]]);
      ao[0][dt] = MFMA(pa00, vv0, ao[0][dt]);
      ao[0][dt] = MFMA(pa01, vv1, ao[0][dt]);
      ao[1][dt] = MFMA(pa10, vv0, ao[1][dt]);
      ao[1][dt] = MFMA(pa11, vv1, ao[1][dt]);
    }
  }

  // epilogue: direct normalize + store (no cross-wave merge needed)
#pragma unroll
  for (int nt = 0; nt < 2; nt++) {
    float inv[4];
#pragma unroll
    for (int r = 0; r < 4; r++)
      inv[r] = 1.0f / (dn[nt][r] + 1e-8f);
#pragma unroll
    for (int dt = 0; dt < 4; dt++) {
#pragma unroll
      for (int r = 0; r < 4; r++) {
        float v = ao[nt][dt][r] * inv[r];
        int s = qt * 128 + wv * 32 + nt * 16 + quad * 4 + r;
        out[((size_t)b * 2048 + s) * 1024 + h * 64 + dt * 16 + col] = v;
      }
    }
  }
}

// ---------------- launcher ----------------
extern "C" void kernel_launch(void* const* d_in, const int* in_sizes, int n_in,
                              void* d_out, int out_size, void* d_ws, size_t ws_size,
                              hipStream_t stream) {
  const float* x  = (const float*)d_in[0];
  const float* Wq = (const float*)d_in[1];
  const float* bq = (const float*)d_in[2];
  const float* Wk = (const float*)d_in[3];
  const float* bk = (const float*)d_in[4];
  const float* Wv = (const float*)d_in[5];
  const float* bv = (const float*)d_in[6];
  float* out = (float*)d_out;

  char* ws = (char*)d_ws;
  u16_t* xb  = (u16_t*)(ws);                 // 8 MB   x bf16 [4096][1024]
  u16_t* Wt  = (u16_t*)(ws + 8388608);       // 6 MB   Wt bf16 [3072][1024]
  u16_t* Qb  = (u16_t*)(ws + 14680064);      // 8 MB   Q bf16 [bh][s][dk] (pre-scaled)
  u16_t* Kb  = (u16_t*)(ws + 23068672);      // 8 MB   K bf16 [bh][s][dk]
  u16_t* Vtb = (u16_t*)(ws + 31457280);      // 8 MB   V^T bf16 [bh][dk][s]

  hipLaunchKernelGGL(k_prep, dim3(4864), dim3(256), 0, stream, x, Wq, Wk, Wv, xb, Wt);
  hipLaunchKernelGGL(k_gemm_qkv, dim3(256), dim3(512), 0, stream,
                     xb, Wt, bq, bk, bv, Qb, Kb, Vtb);
  hipLaunchKernelGGL(k_attn, dim3(512), dim3(256), 0, stream, Qb, Kb, Vtb, out);
}

// Round 10
// 156.960 us; speedup vs baseline: 1.1143x; 1.0189x over previous
//
#include <hip/hip_runtime.h>
#include <hip/hip_bf16.h>
#include <stdint.h>

typedef __bf16 bf16x8 __attribute__((ext_vector_type(8)));
typedef __bf16 bf16x4 __attribute__((ext_vector_type(4)));
typedef float  f32x4  __attribute__((ext_vector_type(4)));
typedef short  s16x4  __attribute__((ext_vector_type(4)));
typedef short  s16x8  __attribute__((ext_vector_type(8)));
typedef unsigned short u16_t;

#define MFMA(a, b, c)   __builtin_amdgcn_mfma_f32_16x16x32_bf16((a), (b), (c), 0, 0, 0)

// concat two s16x4 halves into a bf16x8 MFMA operand
__device__ __forceinline__ bf16x8 cat8(s16x4 a, s16x4 b) {
  s16x8 t = __builtin_shufflevector(a, b, 0, 1, 2, 3, 4, 5, 6, 7);
  return *(bf16x8*)&t;
}
__device__ __forceinline__ bf16x8 b8(s16x8 v) {
  bf16x8 r; __builtin_memcpy(&r, &v, 16); return r;
}

// async global->LDS, 16B per lane; LDS dest is wave-uniform base + lane*16
__device__ __forceinline__ void cp16(const void* g, void* l) {
  __builtin_amdgcn_global_load_lds(
      (const __attribute__((address_space(1))) unsigned int*)g,
      (__attribute__((address_space(3))) unsigned int*)l, 16, 0, 0);
}

// ---------------- kernel 1: fused x-convert + W-transpose-convert ----------------
__global__ __launch_bounds__(256) void k_prep(const float* __restrict__ x,
                                              const float* __restrict__ W0,
                                              const float* __restrict__ W1,
                                              const float* __restrict__ W2,
                                              u16_t* __restrict__ xb,
                                              u16_t* __restrict__ Wt) {
  __shared__ u16_t T[64][65];
  int bx = blockIdx.x, t = threadIdx.x;
  if (bx < 4096) {
    int i = bx * 256 + t;
    float4 f = ((const float4*)x)[i];
    bf16x4 o = {(__bf16)f.x, (__bf16)f.y, (__bf16)f.z, (__bf16)f.w};
    *(bf16x4*)&xb[(size_t)i * 4] = o;
    return;
  }
  int j = bx - 4096;
  int nx = j & 15, ny = (j >> 4) & 15, z = j >> 8;
  const float* W = z == 0 ? W0 : (z == 1 ? W1 : W2);
  int k0 = ny * 64, n0 = nx * 64;
#pragma unroll
  for (int i = 0; i < 16; i++) {
    int e = i * 256 + t, r = e >> 6, c = e & 63;
    __bf16 hv = (__bf16)W[(size_t)(k0 + r) * 1024 + n0 + c];
    T[r][c] = *(u16_t*)&hv;
  }
  __syncthreads();
  size_t base = ((size_t)z * 1024 + n0) * 1024 + k0;
#pragma unroll
  for (int i = 0; i < 16; i++) {
    int e = i * 256 + t, r = e >> 6, c = e & 63;
    Wt[base + (size_t)r * 1024 + c] = T[c][r];
  }
}

// ---------------- kernel 2: fused QKV GEMM, 256x192 tile, 8-wave, 4-phase/K-tile ----------------
// (round-7 version, kept: correct; not iterating blind below the profiling cutoff.)
__global__ __launch_bounds__(512, 2) void k_gemm_qkv(
    const u16_t* __restrict__ A, const u16_t* __restrict__ Bt,
    const float* __restrict__ bq, const float* __restrict__ bk,
    const float* __restrict__ bv,
    u16_t* __restrict__ Qo, u16_t* __restrict__ Ko, u16_t* __restrict__ Vo) {
  __shared__ u16_t smem[57344];          // 112 KB
  u16_t* As = smem;                      // [buf:16384][half:8192][row*32 + chunk*8], 256 rows
  u16_t* Bs = smem + 32768;              // [buf:12288][half:6144][row*32 + chunk*8], 192 rows

  const int tid = threadIdx.x, lane = tid & 63, wv = tid >> 6;
  const int quad = lane >> 4, col = lane & 15;
  const int wm = wv >> 2, wn = wv & 3;   // 2x4 wave grid; wave owns 128x48 of C

  // XCD swizzle: 256 blocks, 32 consecutive wg per XCD
  int bid = blockIdx.x;
  int wg = (bid & 7) * 32 + (bid >> 3);
  const int tn = (wg & 15) * 192, tm = (wg >> 4) << 8;

  const int r16 = lane >> 2, c4 = lane & 3;
  const int srow = wv * 16 + r16;                    // 0..127 (+128 for second call)
  const int skoff = ((c4 ^ ((r16 >> 1) & 3)) << 3);  // pre-swizzled source chunk (u16)
  const int sdst = srow * 32 + (c4 << 3);            // == wave_base + lane*16B
  const size_t gA0 = (size_t)(tm + srow) * 1024 + skoff;
  const size_t gB0 = (size_t)(tn + srow) * 1024 + skoff;

  f32x4 acc[8][3] = {};

#define STAGE(kt, h, b) do {                                     \
    int dA_ = (b) * 16384 + (h) * 8192 + sdst;                   \
    int dB_ = (b) * 12288 + (h) * 6144 + sdst;                   \
    size_t s_ = (size_t)(kt) * 64 + (h) * 32;                    \
    cp16(A + gA0 + s_, As + dA_);                                \
    cp16(A + gA0 + s_ + (size_t)128 * 1024, As + dA_ + 4096);    \
    cp16(Bt + gB0 + s_, Bs + dB_);                               \
    if (wv < 4)                                                  \
      cp16(Bt + gB0 + s_ + (size_t)128 * 1024, Bs + dB_ + 4096); \
  } while (0)

#define BAR()    asm volatile("s_barrier" ::: "memory")
#define WAITV(N) asm volatile("s_waitcnt vmcnt(" #N ")" ::: "memory")
#define WAITL()  asm volatile("s_waitcnt lgkmcnt(0)" ::: "memory")
#define SCHED0() __builtin_amdgcn_sched_barrier(0)

  STAGE(0, 0, 0);
  STAGE(0, 1, 0);
  WAITV(3);   // publish h0 (light-wave exact, heavy conservative)
  BAR();

  const int swz8 = (((lane >> 4) ^ ((col >> 1) & 3)) << 3);
  const int abase = (wm * 128 + col) * 32 + swz8;
  const int bbase = (wn * 48 + col) * 32 + swz8;

  for (int t = 0; t < 16; ++t) {
    const int cur = t & 1, nxt = cur ^ 1;
    const u16_t* Ap = As + cur * 16384;
    const u16_t* Bp = Bs + cur * 12288;
    bf16x8 af[4], bf[3];

    // ---- P0: ks=0, mt 0-3 ----
#pragma unroll
    for (int i = 0; i < 4; i++) af[i] = *(const bf16x8*)&Ap[abase + i * 512];
#pragma unroll
    for (int j = 0; j < 3; j++) bf[j] = *(const bf16x8*)&Bp[bbase + j * 512];
    if (t + 1 < 16) STAGE(t + 1, 0, nxt);
    BAR(); WAITL(); SCHED0();
    __builtin_amdgcn_s_setprio(1);
#pragma unroll
    for (int i = 0; i < 4; i++)
#pragma unroll
      for (int j = 0; j < 3; j++) acc[i][j] = MFMA(af[i], bf[j], acc[i][j]);
    __builtin_amdgcn_s_setprio(0);
    BAR();

    // ---- P1: ks=0, mt 4-7 (reuse bf) ----
#pragma unroll
    for (int i = 0; i < 4; i++) af[i] = *(const bf16x8*)&Ap[abase + (i + 4) * 512];
    if (t + 1 < 16) { STAGE(t + 1, 1, nxt); WAITV(6); }  // publish (t,h1)
    else            { WAITV(0); }                        // final tile: drain h1
    BAR(); WAITL(); SCHED0();
    __builtin_amdgcn_s_setprio(1);
#pragma unroll
    for (int i = 0; i < 4; i++)
#pragma unroll
      for (int j = 0; j < 3; j++) acc[i + 4][j] = MFMA(af[i], bf[j], acc[i + 4][j]);
    __builtin_amdgcn_s_setprio(0);
    BAR();

    // ---- P2: ks=1, mt 0-3 ----
#pragma unroll
    for (int i = 0; i < 4; i++) af[i] = *(const bf16x8*)&Ap[8192 + abase + i * 512];
#pragma unroll
    for (int j = 0; j < 3; j++) bf[j] = *(const bf16x8*)&Bp[6144 + bbase + j * 512];
    BAR(); WAITL(); SCHED0();
    __builtin_amdgcn_s_setprio(1);
#pragma unroll
    for (int i = 0; i < 4; i++)
#pragma unroll
      for (int j = 0; j < 3; j++) acc[i][j] = MFMA(af[i], bf[j], acc[i][j]);
    __builtin_amdgcn_s_setprio(0);
    BAR();

    // ---- P3: ks=1, mt 4-7 ----
#pragma unroll
    for (int i = 0; i < 4; i++) af[i] = *(const bf16x8*)&Ap[8192 + abase + (i + 4) * 512];
    if (t + 1 < 16) WAITV(3);   // publish (t+1,h0)
    WAITL();                    // reads of cur buf done before bar
    BAR(); SCHED0();
    __builtin_amdgcn_s_setprio(1);
#pragma unroll
    for (int i = 0; i < 4; i++)
#pragma unroll
      for (int j = 0; j < 3; j++) acc[i + 4][j] = MFMA(af[i], bf[j], acc[i + 4][j]);
    __builtin_amdgcn_s_setprio(0);
    BAR();
  }

#undef STAGE

  // epilogue: per-(wn,nt) fragment mat select (tile can span Q|K|V boundaries)
#pragma unroll
  for (int nt = 0; nt < 3; nt++) {
    int gn = tn + wn * 48 + nt * 16 + col;
    int mat = gn >> 10, d = gn & 1023, h = d >> 6, dk = d & 63;
    const float* bias = mat == 0 ? bq : (mat == 1 ? bk : bv);
    float bb = bias[d];
    if (mat == 2) {
#pragma unroll
      for (int mt = 0; mt < 8; mt++) {
        int gm = tm + wm * 128 + mt * 16 + quad * 4;
        int b = gm >> 11, s = gm & 2047;
        bf16x4 pk4;
#pragma unroll
        for (int r = 0; r < 4; r++) pk4[r] = (__bf16)(acc[mt][nt][r] + bb);
        *(bf16x4*)&Vo[((size_t)((b * 16 + h) * 64 + dk)) * 2048 + s] = pk4;
      }
    } else {
      u16_t* O = mat == 0 ? Qo : Ko;
      const float scl = mat == 0 ? 0.18033688011112042f : 1.0f;  // log2(e)/8 in Q
#pragma unroll
      for (int mt = 0; mt < 8; mt++) {
#pragma unroll
        for (int r = 0; r < 4; r++) {
          int gm = tm + wm * 128 + mt * 16 + quad * 4 + r;
          int b = gm >> 11, s = gm & 2047;
          __bf16 hv = (__bf16)((acc[mt][nt][r] + bb) * scl);
          O[((size_t)((b * 16 + h) * 2048 + s)) * 64 + dk] = *(u16_t*)&hv;
        }
      }
    }
  }
}

// ---------------- kernel 3: fused attention (v13 = v12 + KVBLK 64->128) ----------------
// 4 waves x 32 full q-rows; 128-key K-tile = TWO 64-key subtiles laid out exactly like
// v12's verified [64][64] tiles (+s*4096 u16 offset) -> all fragment indexing (ka/va,
// slot maps, swizzles) carries over verbatim. Steps 32 -> 16: barrier + drain count
// halves at constant MFMA/exp work. P-state p[sub][nt][g], all statically indexed.
// LDS 80 KB (Q 16 + K dbuf 32 + V dbuf 32) -> 2 blocks/CU == grid 512.
__global__ __launch_bounds__(256, 2) void k_attn(const u16_t* __restrict__ Q,
                                                 const u16_t* __restrict__ K,
                                                 const u16_t* __restrict__ Vt,
                                                 float* __restrict__ out) {
  __shared__ u16_t smem[40960];        // 80 KB
  u16_t* Qs  = smem;                   // 16 KB: Q staging [128][64]
  u16_t* Ksb = smem + 8192;            // 32 KB dbuf: K tiles [2 sub][64k][64d]
  u16_t* Vsb = smem + 24576;           // 32 KB dbuf: V^T tiles [2 sub][64d][64k]
  const int tid = threadIdx.x, lane = tid & 63, wv = tid >> 6;
  const int quad = lane >> 4, col = lane & 15;

  // XCD swizzle: bid&7 = XCD; per XCD: 4 head-groups x 16 qt -> K/V (2 MB) fit 4 MB L2
  const int bid = blockIdx.x;
  const int bh = (bid & 7) + 8 * ((bid >> 3) >> 4);
  const int qt = (bid >> 3) & 15;
  const int b = bh >> 4, h = bh & 15;
  const int r8 = lane >> 3, c8 = lane & 7;

  const u16_t* Qg = Q + ((size_t)bh * 2048 + qt * 128) * 64;
  const u16_t* Kg = K + (size_t)bh * 2048 * 64;
  const u16_t* Vg = Vt + (size_t)bh * 64 * 2048;

  // staging geometry (hoisted): per 64x64 subtile, 2 cp16 per wave (v12 geometry)
  const int lch  = c8 ^ r8;
  const int row0 = (wv * 2) * 8 + r8, row1 = (wv * 2 + 1) * 8 + r8;
  const int ldst0 = (wv * 2) * 512 + lane * 8;
  const int ldst1 = (wv * 2 + 1) * 512 + lane * 8;
  const int gk0 = row0 * 64 + lch * 8,   gk1 = row1 * 64 + lch * 8;
  const int gv0 = row0 * 2048 + lch * 8, gv1 = row1 * 2048 + lch * 8;

  // prologue: Q (16 chunks, 4/wave) + K tile 0 (both subtiles)
#pragma unroll
  for (int i = 0; i < 4; i++) {
    int c = wv * 4 + i;
    cp16(Qg + (c * 8 + r8) * 64 + lch * 8, Qs + c * 512 + lane * 8);
  }
  cp16(Kg + gk0, Ksb + ldst0);
  cp16(Kg + gk1, Ksb + ldst1);
  cp16(Kg + 4096 + gk0, Ksb + 4096 + ldst0);
  cp16(Kg + 4096 + gk1, Ksb + 4096 + ldst1);
  __syncthreads();

  // Q fragments (this wave's 32 q = rows wv*32..wv*32+31) -> registers
  bf16x8 qf[2][2];
#pragma unroll
  for (int nt = 0; nt < 2; nt++)
#pragma unroll
    for (int ks = 0; ks < 2; ks++) {
      int row = wv * 32 + nt * 16 + col;
      qf[nt][ks] = *(const bf16x8*)&Qs[row * 64 + (((ks * 4 + quad) ^ (row & 7)) * 8)];
    }

  // hoisted fragment addresses (loop-invariant, valid within each 64x64 subtile)
  int ka[2][4];
#pragma unroll
  for (int ks = 0; ks < 2; ks++)
#pragma unroll
    for (int mt = 0; mt < 4; mt++) {
      int row = mt * 16 + col;
      ka[ks][mt] = row * 64 + (((ks * 4 + quad) ^ (row & 7)) * 8);
    }
  int va0[2][4], va1[2][4];
#pragma unroll
  for (int g = 0; g < 2; g++)
#pragma unroll
    for (int dt = 0; dt < 4; dt++) {
      int row = dt * 16 + col;
      int cc = g * 4 + (quad >> 1);
      va0[g][dt] = row * 64 + ((cc ^ (row & 7)) * 8) + (quad & 1) * 4;
      va1[g][dt] = row * 64 + (((cc + 2) ^ (row & 7)) * 8) + (quad & 1) * 4;
    }

  const short one_bf = (short)0x3F80;  // bf16 1.0
  s16x8 ones8s = {one_bf, one_bf, one_bf, one_bf, one_bf, one_bf, one_bf, one_bf};
  const bf16x8 ones8 = *(bf16x8*)&ones8s;
  const f32x4 z4 = {0.f, 0.f, 0.f, 0.f};

  f32x4 ao[2][4] = {};
  f32x4 dn[2] = {};
  s16x8 pA[2][2][2] = {}, pB[2][2][2] = {};   // P[sub][nt][g], elem = (mt&1)*4+r

  // one step = one 128-key tile. stage K(KT+1)->Ksb[CUR^1], V(KT)->Vsb[CUR];
  // QK^T(KT) from Ksb[CUR] (2 subs); PV(KT-1) from Vsb[CUR^1] with PFR; exp -> PFW.
#define ATTN_STEP(KT, CUR, PFW, PFR, DO_PV, DO_PRE) do {                              \
    const u16_t* Kc = Ksb + (CUR) * 8192;                                             \
    const u16_t* Vp = Vsb + ((CUR) ^ 1) * 8192;                                       \
    u16_t* Kn = Ksb + ((CUR) ^ 1) * 8192;                                             \
    u16_t* Vn = Vsb + (CUR) * 8192;                                                   \
    if (DO_PRE) {                                                                     \
      const u16_t* kb = Kg + (size_t)((KT) + 1) * 8192;                               \
      cp16(kb + gk0, Kn + ldst0);                                                     \
      cp16(kb + gk1, Kn + ldst1);                                                     \
      cp16(kb + 4096 + gk0, Kn + 4096 + ldst0);                                       \
      cp16(kb + 4096 + gk1, Kn + 4096 + ldst1);                                       \
    }                                                                                 \
    {                                                                                 \
      const u16_t* vb = Vg + (size_t)(KT) * 128;                                      \
      cp16(vb + gv0, Vn + ldst0);                                                     \
      cp16(vb + gv1, Vn + ldst1);                                                     \
      cp16(vb + 64 + gv0, Vn + 4096 + ldst0);                                         \
      cp16(vb + 64 + gv1, Vn + 4096 + ldst1);                                         \
    }                                                                                 \
    __builtin_amdgcn_s_setprio(1);                                                    \
    _Pragma("unroll")                                                                 \
    for (int s = 0; s < 2; s++) {                                                     \
      const u16_t* Ks_ = Kc + s * 4096;                                               \
      f32x4 sc[4][2];                                                                 \
      _Pragma("unroll")                                                               \
      for (int ks = 0; ks < 2; ks++) {                                                \
        bf16x8 kf[4];                                                                 \
        _Pragma("unroll")                                                             \
        for (int mt = 0; mt < 4; mt++) kf[mt] = *(const bf16x8*)&Ks_[ka[ks][mt]];     \
        _Pragma("unroll")                                                             \
        for (int mt = 0; mt < 4; mt++)                                                \
          _Pragma("unroll")                                                           \
          for (int nt = 0; nt < 2; nt++)                                              \
            sc[mt][nt] = ks ? MFMA(kf[mt], qf[nt][1], sc[mt][nt])                     \
                            : MFMA(kf[mt], qf[nt][0], z4);                            \
      }                                                                               \
      _Pragma("unroll")                                                               \
      for (int mt = 0; mt < 4; mt++)                                                  \
        _Pragma("unroll")                                                             \
        for (int nt = 0; nt < 2; nt++)                                                \
          _Pragma("unroll")                                                           \
          for (int r = 0; r < 4; r++) {                                               \
            __bf16 e = (__bf16)__builtin_amdgcn_exp2f(sc[mt][nt][r]);                 \
            PFW[s][nt][mt >> 1][(mt & 1) * 4 + r] = *(short*)&e;                      \
          }                                                                           \
    }                                                                                 \
    if (DO_PV) {                                                                      \
      _Pragma("unroll")                                                               \
      for (int s = 0; s < 2; s++) {                                                   \
        const u16_t* Vs_ = Vp + s * 4096;                                             \
        bf16x8 pa00 = b8(PFR[s][0][0]), pa01 = b8(PFR[s][0][1]);                      \
        bf16x8 pa10 = b8(PFR[s][1][0]), pa11 = b8(PFR[s][1][1]);                      \
        _Pragma("unroll")                                                             \
        for (int dt = 0; dt < 4; dt++) {                                              \
          bf16x8 vv0 = cat8(*(const s16x4*)&Vs_[va0[0][dt]],                          \
                            *(const s16x4*)&Vs_[va1[0][dt]]);                         \
          bf16x8 vv1 = cat8(*(const s16x4*)&Vs_[va0[1][dt]],                          \
                            *(const s16x4*)&Vs_[va1[1][dt]]);                         \
          ao[0][dt] = MFMA(pa00, vv0, ao[0][dt]);                                     \
          ao[0][dt] = MFMA(pa01, vv1, ao[0][dt]);                                     \
          ao[1][dt] = MFMA(pa10, vv0, ao[1][dt]);                                     \
          ao[1][dt] = MFMA(pa11, vv1, ao[1][dt]);                                     \
        }                                                                             \
      }                                                                               \
    }                                                                                 \
    _Pragma("unroll")                                                                 \
    for (int s = 0; s < 2; s++) {                                                     \
      dn[0] = MFMA(b8(PFW[s][0][0]), ones8, dn[0]);                                   \
      dn[0] = MFMA(b8(PFW[s][0][1]), ones8, dn[0]);                                   \
      dn[1] = MFMA(b8(PFW[s][1][0]), ones8, dn[1]);                                   \
      dn[1] = MFMA(b8(PFW[s][1][1]), ones8, dn[1]);                                   \
    }                                                                                 \
    __builtin_amdgcn_s_setprio(0);                                                    \
    __syncthreads();                                                                  \
  } while (0)

  // 16 steps over 128-key tiles; peeled first (no PV) and last (no K prefetch)
  ATTN_STEP(0, 0, pA, pB, 0, 1);
#pragma unroll 1
  for (int kt2 = 0; kt2 < 7; kt2++) {
    int kt0 = kt2 * 2 + 1;
    ATTN_STEP(kt0,     1, pB, pA, 1, 1);
    ATTN_STEP(kt0 + 1, 0, pA, pB, 1, 1);
  }
  ATTN_STEP(15, 1, pB, pA, 1, 0);
#undef ATTN_STEP

  // epilogue PV: P(15) in pB, V(15) in Vsb buffer 1 (published by last barrier)
  {
    const u16_t* Vp = Vsb + 8192;
#pragma unroll
    for (int s = 0; s < 2; s++) {
      const u16_t* Vs_ = Vp + s * 4096;
      bf16x8 pa00 = b8(pB[s][0][0]), pa01 = b8(pB[s][0][1]);
      bf16x8 pa10 = b8(pB[s][1][0]), pa11 = b8(pB[s][1][1]);
#pragma unroll
      for (int dt = 0; dt < 4; dt++) {
        bf16x8 vv0 = cat8(*(const s16x4*)&Vs_[va0[0][dt]], *(const s16x4*)&Vs_[va1[0][dt]]);
        bf16x8 vv1 = cat8(*(const s16x4*)&Vs_[va0[1][dt]], *(const s16x4*)&Vs_[va1[1][dt]]);
        ao[0][dt] = MFMA(pa00, vv0, ao[0][dt]);
        ao[0][dt] = MFMA(pa01, vv1, ao[0][dt]);
        ao[1][dt] = MFMA(pa10, vv0, ao[1][dt]);
        ao[1][dt] = MFMA(pa11, vv1, ao[1][dt]);
      }
    }
  }

  // epilogue: direct normalize + store (no cross-wave merge)
#pragma unroll
  for (int nt = 0; nt < 2; nt++) {
    float inv[4];
#pragma unroll
    for (int r = 0; r < 4; r++)
      inv[r] = 1.0f / (dn[nt][r] + 1e-8f);
#pragma unroll
    for (int dt = 0; dt < 4; dt++) {
#pragma unroll
      for (int r = 0; r < 4; r++) {
        float v = ao[nt][dt][r] * inv[r];
        int s = qt * 128 + wv * 32 + nt * 16 + quad * 4 + r;
        out[((size_t)b * 2048 + s) * 1024 + h * 64 + dt * 16 + col] = v;
      }
    }
  }
}

// ---------------- launcher ----------------
extern "C" void kernel_launch(void* const* d_in, const int* in_sizes, int n_in,
                              void* d_out, int out_size, void* d_ws, size_t ws_size,
                              hipStream_t stream) {
  const float* x  = (const float*)d_in[0];
  const float* Wq = (const float*)d_in[1];
  const float* bq = (const float*)d_in[2];
  const float* Wk = (const float*)d_in[3];
  const float* bk = (const float*)d_in[4];
  const float* Wv = (const float*)d_in[5];
  const float* bv = (const float*)d_in[6];
  float* out = (float*)d_out;

  char* ws = (char*)d_ws;
  u16_t* xb  = (u16_t*)(ws);                 // 8 MB   x bf16 [4096][1024]
  u16_t* Wt  = (u16_t*)(ws + 8388608);       // 6 MB   Wt bf16 [3072][1024]
  u16_t* Qb  = (u16_t*)(ws + 14680064);      // 8 MB   Q bf16 [bh][s][dk] (pre-scaled)
  u16_t* Kb  = (u16_t*)(ws + 23068672);      // 8 MB   K bf16 [bh][s][dk]
  u16_t* Vtb = (u16_t*)(ws + 31457280);      // 8 MB   V^T bf16 [bh][dk][s]

  hipLaunchKernelGGL(k_prep, dim3(4864), dim3(256), 0, stream, x, Wq, Wk, Wv, xb, Wt);
  hipLaunchKernelGGL(k_gemm_qkv, dim3(256), dim3(512), 0, stream,
                     xb, Wt, bq, bk, bv, Qb, Kb, Vtb);
  hipLaunchKernelGGL(k_attn, dim3(512), dim3(256), 0, stream, Qb, Kb, Vtb, out);
}

// Round 11
// 153.674 us; speedup vs baseline: 1.1381x; 1.0214x over previous
//
#include <hip/hip_runtime.h>
#include <hip/hip_bf16.h>
#include <stdint.h>

typedef __bf16 bf16x8 __attribute__((ext_vector_type(8)));
typedef __bf16 bf16x4 __attribute__((ext_vector_type(4)));
typedef float  f32x4  __attribute__((ext_vector_type(4)));
typedef short  s16x4  __attribute__((ext_vector_type(4)));
typedef short  s16x8  __attribute__((ext_vector_type(8)));
typedef unsigned short u16_t;

#define MFMA(a, b, c)   __builtin_amdgcn_mfma_f32_16x16x32_bf16((a), (b), (c), 0, 0, 0)

// concat two s16x4 halves into a bf16x8 MFMA operand
__device__ __forceinline__ bf16x8 cat8(s16x4 a, s16x4 b) {
  s16x8 t = __builtin_shufflevector(a, b, 0, 1, 2, 3, 4, 5, 6, 7);
  return *(bf16x8*)&t;
}
__device__ __forceinline__ bf16x8 b8(s16x8 v) {
  bf16x8 r; __builtin_memcpy(&r, &v, 16); return r;
}

// async global->LDS, 16B per lane; LDS dest is wave-uniform base + lane*16
__device__ __forceinline__ void cp16(const void* g, void* l) {
  __builtin_amdgcn_global_load_lds(
      (const __attribute__((address_space(1))) unsigned int*)g,
      (__attribute__((address_space(3))) unsigned int*)l, 16, 0, 0);
}

// ---------------- kernel 1: fused x-convert + W-transpose-convert ----------------
__global__ __launch_bounds__(256) void k_prep(const float* __restrict__ x,
                                              const float* __restrict__ W0,
                                              const float* __restrict__ W1,
                                              const float* __restrict__ W2,
                                              u16_t* __restrict__ xb,
                                              u16_t* __restrict__ Wt) {
  __shared__ u16_t T[64][65];
  int bx = blockIdx.x, t = threadIdx.x;
  if (bx < 4096) {
    int i = bx * 256 + t;
    float4 f = ((const float4*)x)[i];
    bf16x4 o = {(__bf16)f.x, (__bf16)f.y, (__bf16)f.z, (__bf16)f.w};
    *(bf16x4*)&xb[(size_t)i * 4] = o;
    return;
  }
  int j = bx - 4096;
  int nx = j & 15, ny = (j >> 4) & 15, z = j >> 8;
  const float* W = z == 0 ? W0 : (z == 1 ? W1 : W2);
  int k0 = ny * 64, n0 = nx * 64;
#pragma unroll
  for (int i = 0; i < 16; i++) {
    int e = i * 256 + t, r = e >> 6, c = e & 63;
    __bf16 hv = (__bf16)W[(size_t)(k0 + r) * 1024 + n0 + c];
    T[r][c] = *(u16_t*)&hv;
  }
  __syncthreads();
  size_t base = ((size_t)z * 1024 + n0) * 1024 + k0;
#pragma unroll
  for (int i = 0; i < 16; i++) {
    int e = i * 256 + t, r = e >> 6, c = e & 63;
    Wt[base + (size_t)r * 1024 + c] = T[c][r];
  }
}

// ---------------- kernel 2: fused QKV GEMM, 256x192 tile, 8-wave, 2-barrier/tile ----------------
// Round-11: barrier-count fix. All 4 phases of a tile read the SAME cur buffer -> zero
// intra-tile LDS hazards; the old 8-barriers/tile (128 total) were structural overhead.
// Minimal-correct: 2 barriers/tile (one per k-half publish). Per tile t:
//   STAGE(t+1,h0); P0+P1(cur.h0); WAITV(3); BAR;   // publishes h-half issued LAST tile
//   STAGE(t+1,h1); P2+P3(cur.h1); WAITV(3); BAR;   // counted, never 0 mid-loop
// WAR safety: buf nxt last read at tile t-1, whose end barrier precedes these issues.
// WAITV(3): light waves (3 loads/STAGE) exact; heavy (4) conservatively drain 1 extra.
__global__ __launch_bounds__(512, 2) void k_gemm_qkv(
    const u16_t* __restrict__ A, const u16_t* __restrict__ Bt,
    const float* __restrict__ bq, const float* __restrict__ bk,
    const float* __restrict__ bv,
    u16_t* __restrict__ Qo, u16_t* __restrict__ Ko, u16_t* __restrict__ Vo) {
  __shared__ u16_t smem[57344];          // 112 KB
  u16_t* As = smem;                      // [buf:16384][half:8192][row*32 + chunk*8], 256 rows
  u16_t* Bs = smem + 32768;              // [buf:12288][half:6144][row*32 + chunk*8], 192 rows

  const int tid = threadIdx.x, lane = tid & 63, wv = tid >> 6;
  const int quad = lane >> 4, col = lane & 15;
  const int wm = wv >> 2, wn = wv & 3;   // 2x4 wave grid; wave owns 128x48 of C

  // XCD swizzle: 256 blocks, 32 consecutive wg per XCD
  int bid = blockIdx.x;
  int wg = (bid & 7) * 32 + (bid >> 3);
  const int tn = (wg & 15) * 192, tm = (wg >> 4) << 8;

  const int r16 = lane >> 2, c4 = lane & 3;
  const int srow = wv * 16 + r16;                    // 0..127 (+128 for second call)
  const int skoff = ((c4 ^ ((r16 >> 1) & 3)) << 3);  // pre-swizzled source chunk (u16)
  const int sdst = srow * 32 + (c4 << 3);            // == wave_base + lane*16B
  const size_t gA0 = (size_t)(tm + srow) * 1024 + skoff;
  const size_t gB0 = (size_t)(tn + srow) * 1024 + skoff;

  f32x4 acc[8][3] = {};

#define STAGE(kt, h, b) do {                                     \
    int dA_ = (b) * 16384 + (h) * 8192 + sdst;                   \
    int dB_ = (b) * 12288 + (h) * 6144 + sdst;                   \
    size_t s_ = (size_t)(kt) * 64 + (h) * 32;                    \
    cp16(A + gA0 + s_, As + dA_);                                \
    cp16(A + gA0 + s_ + (size_t)128 * 1024, As + dA_ + 4096);    \
    cp16(Bt + gB0 + s_, Bs + dB_);                               \
    if (wv < 4)                                                  \
      cp16(Bt + gB0 + s_ + (size_t)128 * 1024, Bs + dB_ + 4096); \
  } while (0)

#define BAR()    asm volatile("s_barrier" ::: "memory")
#define WAITV(N) asm volatile("s_waitcnt vmcnt(" #N ")" ::: "memory")

  STAGE(0, 0, 0);
  STAGE(0, 1, 0);
  WAITV(3);   // h0 done (light exact; heavy drains 1 extra of h1 -- safe)
  BAR();

  const int swz8 = (((lane >> 4) ^ ((col >> 1) & 3)) << 3);
  const int abase = (wm * 128 + col) * 32 + swz8;
  const int bbase = (wn * 48 + col) * 32 + swz8;

  for (int t = 0; t < 16; ++t) {
    const int cur = t & 1, nxt = cur ^ 1;
    const u16_t* Ap = As + cur * 16384;
    const u16_t* Bp = Bs + cur * 12288;
    bf16x8 af[4], bf[3];

    // ---- first half-tile: ks=0 (cur.h0), all 8 mt ----
    if (t + 1 < 16) STAGE(t + 1, 0, nxt);
    __builtin_amdgcn_s_setprio(1);
#pragma unroll
    for (int i = 0; i < 4; i++) af[i] = *(const bf16x8*)&Ap[abase + i * 512];
#pragma unroll
    for (int j = 0; j < 3; j++) bf[j] = *(const bf16x8*)&Bp[bbase + j * 512];
#pragma unroll
    for (int i = 0; i < 4; i++)
#pragma unroll
      for (int j = 0; j < 3; j++) acc[i][j] = MFMA(af[i], bf[j], acc[i][j]);
#pragma unroll
    for (int i = 0; i < 4; i++) af[i] = *(const bf16x8*)&Ap[abase + (i + 4) * 512];
#pragma unroll
    for (int i = 0; i < 4; i++)
#pragma unroll
      for (int j = 0; j < 3; j++) acc[i + 4][j] = MFMA(af[i], bf[j], acc[i + 4][j]);
    __builtin_amdgcn_s_setprio(0);
    if (t + 1 < 16) WAITV(3);   // publish cur.h1 (issued last tile); h0(t+1) in flight
    else            WAITV(0);   // final tile: drain h1(15)
    BAR();

    // ---- second half-tile: ks=1 (cur.h1), all 8 mt ----
    if (t + 1 < 16) STAGE(t + 1, 1, nxt);
    __builtin_amdgcn_s_setprio(1);
#pragma unroll
    for (int i = 0; i < 4; i++) af[i] = *(const bf16x8*)&Ap[8192 + abase + i * 512];
#pragma unroll
    for (int j = 0; j < 3; j++) bf[j] = *(const bf16x8*)&Bp[6144 + bbase + j * 512];
#pragma unroll
    for (int i = 0; i < 4; i++)
#pragma unroll
      for (int j = 0; j < 3; j++) acc[i][j] = MFMA(af[i], bf[j], acc[i][j]);
#pragma unroll
    for (int i = 0; i < 4; i++) af[i] = *(const bf16x8*)&Ap[8192 + abase + (i + 4) * 512];
#pragma unroll
    for (int i = 0; i < 4; i++)
#pragma unroll
      for (int j = 0; j < 3; j++) acc[i + 4][j] = MFMA(af[i], bf[j], acc[i + 4][j]);
    __builtin_amdgcn_s_setprio(0);
    if (t + 1 < 16) {
      WAITV(3);   // publish h0(t+1); h1(t+1) stays in flight
      BAR();
    }
  }

#undef STAGE

  // epilogue: per-(wn,nt) fragment mat select (tile can span Q|K|V boundaries)
#pragma unroll
  for (int nt = 0; nt < 3; nt++) {
    int gn = tn + wn * 48 + nt * 16 + col;
    int mat = gn >> 10, d = gn & 1023, h = d >> 6, dk = d & 63;
    const float* bias = mat == 0 ? bq : (mat == 1 ? bk : bv);
    float bb = bias[d];
    if (mat == 2) {
#pragma unroll
      for (int mt = 0; mt < 8; mt++) {
        int gm = tm + wm * 128 + mt * 16 + quad * 4;
        int b = gm >> 11, s = gm & 2047;
        bf16x4 pk4;
#pragma unroll
        for (int r = 0; r < 4; r++) pk4[r] = (__bf16)(acc[mt][nt][r] + bb);
        *(bf16x4*)&Vo[((size_t)((b * 16 + h) * 64 + dk)) * 2048 + s] = pk4;
      }
    } else {
      u16_t* O = mat == 0 ? Qo : Ko;
      const float scl = mat == 0 ? 0.18033688011112042f : 1.0f;  // log2(e)/8 in Q
#pragma unroll
      for (int mt = 0; mt < 8; mt++) {
#pragma unroll
        for (int r = 0; r < 4; r++) {
          int gm = tm + wm * 128 + mt * 16 + quad * 4 + r;
          int b = gm >> 11, s = gm & 2047;
          __bf16 hv = (__bf16)((acc[mt][nt][r] + bb) * scl);
          O[((size_t)((b * 16 + h) * 2048 + s)) * 64 + dk] = *(u16_t*)&hv;
        }
      }
    }
  }
}

// ---------------- kernel 3: fused attention (v13 = QBLK 128, KVBLK 128 — unchanged) ----------------
__global__ __launch_bounds__(256, 2) void k_attn(const u16_t* __restrict__ Q,
                                                 const u16_t* __restrict__ K,
                                                 const u16_t* __restrict__ Vt,
                                                 float* __restrict__ out) {
  __shared__ u16_t smem[40960];        // 80 KB
  u16_t* Qs  = smem;                   // 16 KB: Q staging [128][64]
  u16_t* Ksb = smem + 8192;            // 32 KB dbuf: K tiles [2 sub][64k][64d]
  u16_t* Vsb = smem + 24576;           // 32 KB dbuf: V^T tiles [2 sub][64d][64k]
  const int tid = threadIdx.x, lane = tid & 63, wv = tid >> 6;
  const int quad = lane >> 4, col = lane & 15;

  // XCD swizzle: bid&7 = XCD; per XCD: 4 head-groups x 16 qt -> K/V (2 MB) fit 4 MB L2
  const int bid = blockIdx.x;
  const int bh = (bid & 7) + 8 * ((bid >> 3) >> 4);
  const int qt = (bid >> 3) & 15;
  const int b = bh >> 4, h = bh & 15;
  const int r8 = lane >> 3, c8 = lane & 7;

  const u16_t* Qg = Q + ((size_t)bh * 2048 + qt * 128) * 64;
  const u16_t* Kg = K + (size_t)bh * 2048 * 64;
  const u16_t* Vg = Vt + (size_t)bh * 64 * 2048;

  // staging geometry (hoisted): per 64x64 subtile, 2 cp16 per wave
  const int lch  = c8 ^ r8;
  const int row0 = (wv * 2) * 8 + r8, row1 = (wv * 2 + 1) * 8 + r8;
  const int ldst0 = (wv * 2) * 512 + lane * 8;
  const int ldst1 = (wv * 2 + 1) * 512 + lane * 8;
  const int gk0 = row0 * 64 + lch * 8,   gk1 = row1 * 64 + lch * 8;
  const int gv0 = row0 * 2048 + lch * 8, gv1 = row1 * 2048 + lch * 8;

  // prologue: Q (16 chunks, 4/wave) + K tile 0 (both subtiles)
#pragma unroll
  for (int i = 0; i < 4; i++) {
    int c = wv * 4 + i;
    cp16(Qg + (c * 8 + r8) * 64 + lch * 8, Qs + c * 512 + lane * 8);
  }
  cp16(Kg + gk0, Ksb + ldst0);
  cp16(Kg + gk1, Ksb + ldst1);
  cp16(Kg + 4096 + gk0, Ksb + 4096 + ldst0);
  cp16(Kg + 4096 + gk1, Ksb + 4096 + ldst1);
  __syncthreads();

  // Q fragments (this wave's 32 q = rows wv*32..wv*32+31) -> registers
  bf16x8 qf[2][2];
#pragma unroll
  for (int nt = 0; nt < 2; nt++)
#pragma unroll
    for (int ks = 0; ks < 2; ks++) {
      int row = wv * 32 + nt * 16 + col;
      qf[nt][ks] = *(const bf16x8*)&Qs[row * 64 + (((ks * 4 + quad) ^ (row & 7)) * 8)];
    }

  // hoisted fragment addresses (loop-invariant, valid within each 64x64 subtile)
  int ka[2][4];
#pragma unroll
  for (int ks = 0; ks < 2; ks++)
#pragma unroll
    for (int mt = 0; mt < 4; mt++) {
      int row = mt * 16 + col;
      ka[ks][mt] = row * 64 + (((ks * 4 + quad) ^ (row & 7)) * 8);
    }
  int va0[2][4], va1[2][4];
#pragma unroll
  for (int g = 0; g < 2; g++)
#pragma unroll
    for (int dt = 0; dt < 4; dt++) {
      int row = dt * 16 + col;
      int cc = g * 4 + (quad >> 1);
      va0[g][dt] = row * 64 + ((cc ^ (row & 7)) * 8) + (quad & 1) * 4;
      va1[g][dt] = row * 64 + (((cc + 2) ^ (row & 7)) * 8) + (quad & 1) * 4;
    }

  const short one_bf = (short)0x3F80;  // bf16 1.0
  s16x8 ones8s = {one_bf, one_bf, one_bf, one_bf, one_bf, one_bf, one_bf, one_bf};
  const bf16x8 ones8 = *(bf16x8*)&ones8s;
  const f32x4 z4 = {0.f, 0.f, 0.f, 0.f};

  f32x4 ao[2][4] = {};
  f32x4 dn[2] = {};
  s16x8 pA[2][2][2] = {}, pB[2][2][2] = {};   // P[sub][nt][g], elem = (mt&1)*4+r

#define ATTN_STEP(KT, CUR, PFW, PFR, DO_PV, DO_PRE) do {                              \
    const u16_t* Kc = Ksb + (CUR) * 8192;                                             \
    const u16_t* Vp = Vsb + ((CUR) ^ 1) * 8192;                                       \
    u16_t* Kn = Ksb + ((CUR) ^ 1) * 8192;                                             \
    u16_t* Vn = Vsb + (CUR) * 8192;                                                   \
    if (DO_PRE) {                                                                     \
      const u16_t* kb = Kg + (size_t)((KT) + 1) * 8192;                               \
      cp16(kb + gk0, Kn + ldst0);                                                     \
      cp16(kb + gk1, Kn + ldst1);                                                     \
      cp16(kb + 4096 + gk0, Kn + 4096 + ldst0);                                       \
      cp16(kb + 4096 + gk1, Kn + 4096 + ldst1);                                       \
    }                                                                                 \
    {                                                                                 \
      const u16_t* vb = Vg + (size_t)(KT) * 128;                                      \
      cp16(vb + gv0, Vn + ldst0);                                                     \
      cp16(vb + gv1, Vn + ldst1);                                                     \
      cp16(vb + 64 + gv0, Vn + 4096 + ldst0);                                         \
      cp16(vb + 64 + gv1, Vn + 4096 + ldst1);                                         \
    }                                                                                 \
    __builtin_amdgcn_s_setprio(1);                                                    \
    _Pragma("unroll")                                                                 \
    for (int s = 0; s < 2; s++) {                                                     \
      const u16_t* Ks_ = Kc + s * 4096;                                               \
      f32x4 sc[4][2];                                                                 \
      _Pragma("unroll")                                                               \
      for (int ks = 0; ks < 2; ks++) {                                                \
        bf16x8 kf[4];                                                                 \
        _Pragma("unroll")                                                             \
        for (int mt = 0; mt < 4; mt++) kf[mt] = *(const bf16x8*)&Ks_[ka[ks][mt]];     \
        _Pragma("unroll")                                                             \
        for (int mt = 0; mt < 4; mt++)                                                \
          _Pragma("unroll")                                                           \
          for (int nt = 0; nt < 2; nt++)                                              \
            sc[mt][nt] = ks ? MFMA(kf[mt], qf[nt][1], sc[mt][nt])                     \
                            : MFMA(kf[mt], qf[nt][0], z4);                            \
      }                                                                               \
      _Pragma("unroll")                                                               \
      for (int mt = 0; mt < 4; mt++)                                                  \
        _Pragma("unroll")                                                             \
        for (int nt = 0; nt < 2; nt++)                                                \
          _Pragma("unroll")                                                           \
          for (int r = 0; r < 4; r++) {                                               \
            __bf16 e = (__bf16)__builtin_amdgcn_exp2f(sc[mt][nt][r]);                 \
            PFW[s][nt][mt >> 1][(mt & 1) * 4 + r] = *(short*)&e;                      \
          }                                                                           \
    }                                                                                 \
    if (DO_PV) {                                                                      \
      _Pragma("unroll")                                                               \
      for (int s = 0; s < 2; s++) {                                                   \
        const u16_t* Vs_ = Vp + s * 4096;                                             \
        bf16x8 pa00 = b8(PFR[s][0][0]), pa01 = b8(PFR[s][0][1]);                      \
        bf16x8 pa10 = b8(PFR[s][1][0]), pa11 = b8(PFR[s][1][1]);                      \
        _Pragma("unroll")                                                             \
        for (int dt = 0; dt < 4; dt++) {                                              \
          bf16x8 vv0 = cat8(*(const s16x4*)&Vs_[va0[0][dt]],                          \
                            *(const s16x4*)&Vs_[va1[0][dt]]);                         \
          bf16x8 vv1 = cat8(*(const s16x4*)&Vs_[va0[1][dt]],                          \
                            *(const s16x4*)&Vs_[va1[1][dt]]);                         \
          ao[0][dt] = MFMA(pa00, vv0, ao[0][dt]);                                     \
          ao[0][dt] = MFMA(pa01, vv1, ao[0][dt]);                                     \
          ao[1][dt] = MFMA(pa10, vv0, ao[1][dt]);                                     \
          ao[1][dt] = MFMA(pa11, vv1, ao[1][dt]);                                     \
        }                                                                             \
      }                                                                               \
    }                                                                                 \
    _Pragma("unroll")                                                                 \
    for (int s = 0; s < 2; s++) {                                                     \
      dn[0] = MFMA(b8(PFW[s][0][0]), ones8, dn[0]);                                   \
      dn[0] = MFMA(b8(PFW[s][0][1]), ones8, dn[0]);                                   \
      dn[1] = MFMA(b8(PFW[s][1][0]), ones8, dn[1]);                                   \
      dn[1] = MFMA(b8(PFW[s][1][1]), ones8, dn[1]);                                   \
    }                                                                                 \
    __builtin_amdgcn_s_setprio(0);                                                    \
    __syncthreads();                                                                  \
  } while (0)

  // 16 steps over 128-key tiles; peeled first (no PV) and last (no K prefetch)
  ATTN_STEP(0, 0, pA, pB, 0, 1);
#pragma unroll 1
  for (int kt2 = 0; kt2 < 7; kt2++) {
    int kt0 = kt2 * 2 + 1;
    ATTN_STEP(kt0,     1, pB, pA, 1, 1);
    ATTN_STEP(kt0 + 1, 0, pA, pB, 1, 1);
  }
  ATTN_STEP(15, 1, pB, pA, 1, 0);
#undef ATTN_STEP

  // epilogue PV: P(15) in pB, V(15) in Vsb buffer 1 (published by last barrier)
  {
    const u16_t* Vp = Vsb + 8192;
#pragma unroll
    for (int s = 0; s < 2; s++) {
      const u16_t* Vs_ = Vp + s * 4096;
      bf16x8 pa00 = b8(pB[s][0][0]), pa01 = b8(pB[s][0][1]);
      bf16x8 pa10 = b8(pB[s][1][0]), pa11 = b8(pB[s][1][1]);
#pragma unroll
      for (int dt = 0; dt < 4; dt++) {
        bf16x8 vv0 = cat8(*(const s16x4*)&Vs_[va0[0][dt]], *(const s16x4*)&Vs_[va1[0][dt]]);
        bf16x8 vv1 = cat8(*(const s16x4*)&Vs_[va0[1][dt]], *(const s16x4*)&Vs_[va1[1][dt]]);
        ao[0][dt] = MFMA(pa00, vv0, ao[0][dt]);
        ao[0][dt] = MFMA(pa01, vv1, ao[0][dt]);
        ao[1][dt] = MFMA(pa10, vv0, ao[1][dt]);
        ao[1][dt] = MFMA(pa11, vv1, ao[1][dt]);
      }
    }
  }

  // epilogue: direct normalize + store (no cross-wave merge)
#pragma unroll
  for (int nt = 0; nt < 2; nt++) {
    float inv[4];
#pragma unroll
    for (int r = 0; r < 4; r++)
      inv[r] = 1.0f / (dn[nt][r] + 1e-8f);
#pragma unroll
    for (int dt = 0; dt < 4; dt++) {
#pragma unroll
      for (int r = 0; r < 4; r++) {
        float v = ao[nt][dt][r] * inv[r];
        int s = qt * 128 + wv * 32 + nt * 16 + quad * 4 + r;
        out[((size_t)b * 2048 + s) * 1024 + h * 64 + dt * 16 + col] = v;
      }
    }
  }
}

// ---------------- launcher ----------------
extern "C" void kernel_launch(void* const* d_in, const int* in_sizes, int n_in,
                              void* d_out, int out_size, void* d_ws, size_t ws_size,
                              hipStream_t stream) {
  const float* x  = (const float*)d_in[0];
  const float* Wq = (const float*)d_in[1];
  const float* bq = (const float*)d_in[2];
  const float* Wk = (const float*)d_in[3];
  const float* bk = (const float*)d_in[4];
  const float* Wv = (const float*)d_in[5];
  const float* bv = (const float*)d_in[6];
  float* out = (float*)d_out;

  char* ws = (char*)d_ws;
  u16_t* xb  = (u16_t*)(ws);                 // 8 MB   x bf16 [4096][1024]
  u16_t* Wt  = (u16_t*)(ws + 8388608);       // 6 MB   Wt bf16 [3072][1024]
  u16_t* Qb  = (u16_t*)(ws + 14680064);      // 8 MB   Q bf16 [bh][s][dk] (pre-scaled)
  u16_t* Kb  = (u16_t*)(ws + 23068672);      // 8 MB   K bf16 [bh][s][dk]
  u16_t* Vtb = (u16_t*)(ws + 31457280);      // 8 MB   V^T bf16 [bh][dk][s]

  hipLaunchKernelGGL(k_prep, dim3(4864), dim3(256), 0, stream, x, Wq, Wk, Wv, xb, Wt);
  hipLaunchKernelGGL(k_gemm_qkv, dim3(256), dim3(512), 0, stream,
                     xb, Wt, bq, bk, bv, Qb, Kb, Vtb);
  hipLaunchKernelGGL(k_attn, dim3(1024 >> 1), dim3(256), 0, stream, Qb, Kb, Vtb, out);
}